// Round 6
// baseline (2496.016 us; speedup 1.0000x reference)
//
#include <hip/hip_runtime.h>
#include <math.h>

// Problem dims (fixed)
#define N_ 20000
#define E_ 100000
#define B_ 128
#define F_IN_ 14
#define DIM_ 64
#define E_FEAT_ 4
#define MLP_H_ 128
#define EWC_ 4096    // DIM*DIM
#define PC_ 8192     // MLP_H * DIM (P columns)

typedef __attribute__((ext_vector_type(8))) short bf16x8;
typedef __attribute__((ext_vector_type(4))) float f32x4;

__device__ __forceinline__ unsigned short f2bf_rn(float f) {
    unsigned int u = __float_as_uint(f);
    unsigned int r = (u + 0x7fffu + ((u >> 16) & 1u)) >> 16;
    return (unsigned short)r;
}
__device__ __forceinline__ float bf2f(unsigned short h) {
    return __uint_as_float(((unsigned int)h) << 16);
}

// ---------------------------------------------------------------------------
// lin0: out[n,d] = relu(x[n,:] @ lin0_w + b)
__global__ void lin0_kernel(const float* __restrict__ x, const float* __restrict__ w,
                            const float* __restrict__ b, float* __restrict__ out) {
    int idx = blockIdx.x * blockDim.x + threadIdx.x;
    if (idx >= N_ * DIM_) return;
    int n = idx >> 6, d = idx & 63;
    float acc = b[d];
#pragma unroll
    for (int f = 0; f < F_IN_; ++f) acc = fmaf(x[n * F_IN_ + f], w[f * DIM_ + d], acc);
    out[idx] = acc > 0.f ? acc : 0.f;
}

// edge MLP layer 1, ROW-major: h1[e*128 + k] = relu(ea[e,:] @ w1 + b1)[k]
__global__ void mlp1_kernel(const float* __restrict__ ea, const float* __restrict__ w1,
                            const float* __restrict__ b1, float* __restrict__ h1) {
    int idx = blockIdx.x * blockDim.x + threadIdx.x;
    if (idx >= E_ * MLP_H_) return;
    int e = idx >> 7, k = idx & 127;
    float acc = b1[k];
#pragma unroll
    for (int f = 0; f < E_FEAT_; ++f) acc = fmaf(ea[e * E_FEAT_ + f], w1[f * MLP_H_ + k], acc);
    h1[idx] = acc > 0.f ? acc : 0.f;
}

// incoming-edge counts (float, for mean)
__global__ void cnt_kernel(const int* __restrict__ dst, float* __restrict__ cnt) {
    int e = blockIdx.x * blockDim.x + threadIdx.x;
    if (e >= E_) return;
    atomicAdd(&cnt[dst[e]], 1.0f);
}

// batch is SORTED: off_b[b] = lower_bound(batch, b). Replaces atomic histogram.
__global__ void batch_off_kernel(const int* __restrict__ batch, int* __restrict__ off_b) {
    int b = threadIdx.x;
    if (b > B_) return;
    int lo = 0, hi = N_;
    while (lo < hi) {
        int mid = (lo + hi) >> 1;
        if (batch[mid] < b) lo = mid + 1; else hi = mid;
    }
    off_b[b] = lo;
}

// src histogram for counting sort
__global__ void hist_src(const int* __restrict__ src, int* __restrict__ cnt_src) {
    int e = blockIdx.x * blockDim.x + threadIdx.x;
    if (e >= E_) return;
    atomicAdd(&cnt_src[src[e]], 1);
}

// exclusive scan over N_ bins -> src_off[0..N_]
__global__ void scan_src(const int* __restrict__ cnt_src, int* __restrict__ src_off) {
    __shared__ int part[256];
    __shared__ int off[257];
    int t = threadIdx.x;
    const int per = (N_ + 255) / 256;
    int base = t * per;
    int s = 0;
    for (int i = 0; i < per; ++i) { int b = base + i; if (b < N_) s += cnt_src[b]; }
    part[t] = s;
    __syncthreads();
    if (t == 0) {
        int a = 0;
        for (int i = 0; i < 256; ++i) { off[i] = a; a += part[i]; }
        off[256] = a;
    }
    __syncthreads();
    int run = off[t];
    for (int i = 0; i < per; ++i) {
        int b = base + i;
        if (b < N_) { src_off[b] = run; run += cnt_src[b]; }
    }
    if (t == 0) src_off[N_] = off[256];
}

// scatter edges into src-sorted order
__global__ void scatter_src(const int* __restrict__ src, int* __restrict__ cur,
                            const int* __restrict__ src_off, int* __restrict__ eord) {
    int e = blockIdx.x * blockDim.x + threadIdx.x;
    if (e >= E_) return;
    int s = src[e];
    int p = src_off[s] + atomicAdd(&cur[s], 1);
    eord[p] = e;
}

// B prep (once): Bh/Bl[c*64 + i] = bf16 hi/lo of w2[(c>>6)*4096 + i*64 + (c&63)]
__global__ void prep_b(const float* __restrict__ w2,
                       unsigned short* __restrict__ Bh,
                       unsigned short* __restrict__ Bl) {
    int idx = blockIdx.x * blockDim.x + threadIdx.x;
    if (idx >= PC_ * 64) return;
    int c = idx >> 6, i = idx & 63;
    float v = w2[(size_t)(c >> 6) * EWC_ + i * 64 + (c & 63)];
    unsigned short h = f2bf_rn(v);
    Bh[idx] = h;
    Bl[idx] = f2bf_rn(v - bf2f(h));
}

// Q[n,o] = sum_i out[n,i] * b2[i*64+o] — wave/node, b2 staged in LDS
__global__ __launch_bounds__(256) void q_kernel(const float* __restrict__ out,
                                                const float* __restrict__ b2,
                                                float* __restrict__ Q) {
    __shared__ float b2s[64 * 64];
    int tid = threadIdx.x;
#pragma unroll
    for (int it = 0; it < 4; ++it) {
        int i = it * 1024 + tid * 4;
        *(float4*)&b2s[i] = *(const float4*)&b2[i];
    }
    __syncthreads();
    int wv = __builtin_amdgcn_readfirstlane(tid >> 6);
    int n = blockIdx.x * 4 + wv;
    if (n >= N_) return;
    int o = tid & 63;
    float ov = out[(size_t)n * 64 + o];
    float acc = 0.f;
#pragma unroll 8
    for (int i = 0; i < 64; ++i) acc = fmaf(__shfl(ov, i, 64), b2s[i * 64 + o], acc);
    Q[(size_t)n * 64 + o] = acc;
}

// ---------------------------------------------------------------------------
// Fused per-step message kernel. Block = 32 nodes, 4 waves.
// Per k-tile (8 k's): phase A computes P_tile[32 nodes][8 k][64 o] (fp32, LDS)
// via split-bf16 MFMA (3-term); phase B contracts the block's edges
// (src-sorted, node-contiguous per wave) against P_tile, msg in registers.
// Epilogue adds Q and atomically accumulates into agg. P never hits global.
#define GN_ 32
#define TKB_ 8
#define NT_ 16
#define KSTR_ 64
#define NSTR_ 514     // 8*64+2: quad offset 4*514 % 32 = 8 -> conflict-free epilogue writes
#define SLOTS_ 64     // edge slots per wave per group

__global__ __launch_bounds__(256) void msg_fused(const float* __restrict__ out,
                                                 const unsigned short* __restrict__ Bh,
                                                 const unsigned short* __restrict__ Bl,
                                                 const float* __restrict__ h1,
                                                 const float* __restrict__ Q,
                                                 const int* __restrict__ eord,
                                                 const int* __restrict__ dst,
                                                 const int* __restrict__ src_off,
                                                 float* __restrict__ agg) {
    __shared__ float P_s[GN_ * NSTR_];      // 65.8 KB
    __shared__ float h1w_s[256 * 8];        // 8 KB: 4 waves x 64 slots x 8 k
    __shared__ int ej_s[256], ln_s[256], ds_s[256];
    __shared__ int ne_s[GN_ + 1];
    __shared__ int red_s[4];

    int tid = threadIdx.x;
    int lane = tid & 63;
    int wv = tid >> 6;
    int lrow = lane & 15, quad = lane >> 4;
    int nb = blockIdx.x * GN_;

    if (tid <= GN_) ne_s[tid] = src_off[nb + tid];

    // phase-A A-fragments: rows = 32 nodes (2 row-frags), K=64, split hi/lo
    bf16x8 ah[2][2], al[2][2];
#pragma unroll
    for (int rf = 0; rf < 2; ++rf)
#pragma unroll
        for (int ks = 0; ks < 2; ++ks) {
            const float* ap = &out[(size_t)(nb + rf * 16 + lrow) * 64 + ks * 32 + quad * 8];
            float4 v0 = *(const float4*)ap;
            float4 v1 = *(const float4*)(ap + 4);
            float v[8] = {v0.x, v0.y, v0.z, v0.w, v1.x, v1.y, v1.z, v1.w};
#pragma unroll
            for (int i = 0; i < 8; ++i) {
                unsigned short hh = f2bf_rn(v[i]);
                ah[rf][ks][i] = (short)hh;
                al[rf][ks][i] = (short)f2bf_rn(v[i] - bf2f(hh));
            }
        }
    __syncthreads();

    int wbeg = ne_s[wv * 8], wend = ne_s[wv * 8 + 8];
    if (lane == 0) red_s[wv] = (wend - wbeg + SLOTS_ - 1) / SLOTS_;
    __syncthreads();
    int ngrp = max(max(red_s[0], red_s[1]), max(red_s[2], red_s[3]));

#pragma unroll 1
    for (int g = 0; g < ngrp; ++g) {
        // stage this group's edge meta (own-wave region; no barrier needed)
        {
            int pos = wbeg + g * SLOTS_ + lane;
            int ej = -1, lnv = -1, dv = 0;
            if (pos < wend) {
                ej = eord[pos];
                dv = dst[ej];
                int i = wv * 8;
                while (pos >= ne_s[i + 1]) ++i;
                lnv = i;
            }
            ej_s[wv * 64 + lane] = ej;
            ln_s[wv * 64 + lane] = lnv;
            ds_s[wv * 64 + lane] = dv;
        }
        float msg[SLOTS_];
#pragma unroll
        for (int j = 0; j < SLOTS_; ++j) msg[j] = 0.f;

#pragma unroll 1
        for (int t = 0; t < NT_; ++t) {
            // ---- phase A: P_tile for k in [t*8, t*8+8) ----
#pragma unroll
            for (int f = 0; f < 8; ++f) {
                int coff = (wv * 8 + f) * 16;          // within-tile col (kk*64+o)
                int c = t * 512 + coff + lrow;         // global P column
                bf16x8 bhv[2], blv[2];
#pragma unroll
                for (int ks = 0; ks < 2; ++ks) {
                    bhv[ks] = *(const bf16x8*)&Bh[(size_t)c * 64 + ks * 32 + quad * 8];
                    blv[ks] = *(const bf16x8*)&Bl[(size_t)c * 64 + ks * 32 + quad * 8];
                }
                int kk = coff >> 6, o0 = coff & 63;
#pragma unroll
                for (int rf = 0; rf < 2; ++rf) {
                    f32x4 pa = {0.f, 0.f, 0.f, 0.f};
#pragma unroll
                    for (int ks = 0; ks < 2; ++ks) {
                        pa = __builtin_amdgcn_mfma_f32_16x16x32_bf16(ah[rf][ks], bhv[ks], pa, 0, 0, 0);
                        pa = __builtin_amdgcn_mfma_f32_16x16x32_bf16(al[rf][ks], bhv[ks], pa, 0, 0, 0);
                        pa = __builtin_amdgcn_mfma_f32_16x16x32_bf16(ah[rf][ks], blv[ks], pa, 0, 0, 0);
                    }
#pragma unroll
                    for (int r = 0; r < 4; ++r)
                        P_s[(rf * 16 + quad * 4 + r) * NSTR_ + kk * KSTR_ + o0 + lrow] = pa[r];
                }
            }
            __syncthreads();
            // stage h1 tile for own-wave slots (32B per edge, coalesced)
            {
                int k0 = t * TKB_;
#pragma unroll
                for (int i = 0; i < 8; ++i) {
                    int slot = (lane >> 3) + i * 8;
                    int ej = ej_s[wv * 64 + slot];
                    float hv = 0.f;
                    if (ej >= 0) hv = h1[(size_t)ej * 128 + k0 + (lane & 7)];
                    h1w_s[(wv * 64 + slot) * 8 + (lane & 7)] = hv;
                }
            }
            // ---- phase B: per-node pv registers, edges node-contiguous ----
            {
                float pv[8];
                int curln = -1;
#pragma unroll
                for (int j = 0; j < SLOTS_; ++j) {
                    int lnj = ln_s[wv * 64 + j];
                    if (lnj < 0) break;
                    if (lnj != curln) {
                        curln = lnj;
#pragma unroll
                        for (int kk = 0; kk < 8; ++kk)
                            pv[kk] = P_s[lnj * NSTR_ + kk * KSTR_ + lane];
                    }
                    const float4 hA = *(const float4*)&h1w_s[(wv * 64 + j) * 8];
                    const float4 hB = *(const float4*)&h1w_s[(wv * 64 + j) * 8 + 4];
                    float s = pv[0] * hA.x;
                    s = fmaf(pv[1], hA.y, s);
                    s = fmaf(pv[2], hA.z, s);
                    s = fmaf(pv[3], hA.w, s);
                    s = fmaf(pv[4], hB.x, s);
                    s = fmaf(pv[5], hB.y, s);
                    s = fmaf(pv[6], hB.z, s);
                    s = fmaf(pv[7], hB.w, s);
                    msg[j] += s;
                }
            }
            __syncthreads();
        }
        // epilogue: add Q, atomically accumulate into agg
#pragma unroll
        for (int j = 0; j < SLOTS_; ++j) {
            int lnj = ln_s[wv * 64 + j];
            if (lnj < 0) break;
            int d = ds_s[wv * 64 + j];
            float qv = Q[(size_t)(nb + lnj) * 64 + lane];
            atomicAdd(&agg[(size_t)d * 64 + lane], msg[j] + qv);
        }
    }
}

// combine (scatter-mean + root + bias + relu) and GRU cell; 32 nodes/block,
// 8 nodes/wave register tiling, root/h/m staged in LDS, weights streamed (L2).
__global__ __launch_bounds__(256) void gru_kernel(float* __restrict__ out,
                                                  const float* __restrict__ agg,
                                                  const float* __restrict__ cnt,
                                                  const float* __restrict__ root,
                                                  const float* __restrict__ cbias,
                                                  const float* __restrict__ wi,
                                                  const float* __restrict__ wh,
                                                  const float* __restrict__ bi,
                                                  const float* __restrict__ bh) {
    __shared__ float root_s[64 * 64];
    __shared__ float h_s[32 * 64];
    __shared__ float m_s[32 * 64];
    int tid = threadIdx.x;
    int lane = tid & 63;
    int wv = __builtin_amdgcn_readfirstlane(tid >> 6);
    int nb = blockIdx.x * 32;
#pragma unroll
    for (int it = 0; it < 4; ++it) {
        int i = it * 1024 + tid * 4;
        *(float4*)&root_s[i] = *(const float4*)&root[i];
    }
#pragma unroll
    for (int it = 0; it < 2; ++it) {
        int i = it * 1024 + tid * 4;
        *(float4*)&h_s[i] = *(const float4*)&out[(size_t)nb * 64 + i];
    }
    __syncthreads();

    int nbase = nb + wv * 8;
    float a[8];
#pragma unroll
    for (int j = 0; j < 8; ++j) {
        int n = nbase + j;
        float c = cnt[n]; c = c > 1.f ? c : 1.f;
        a[j] = agg[(size_t)n * 64 + lane] / c + cbias[lane];
    }
    for (int i = 0; i < 64; ++i) {
        float rv = root_s[i * 64 + lane];
#pragma unroll
        for (int j = 0; j < 8; ++j)
            a[j] = fmaf(h_s[(wv * 8 + j) * 64 + i], rv, a[j]);
    }
#pragma unroll
    for (int j = 0; j < 8; ++j) {
        float m = a[j] > 0.f ? a[j] : 0.f;
        m_s[(wv * 8 + j) * 64 + lane] = m;
    }
    __syncthreads();

    float gir[8], giz[8], gin[8], ghr[8], ghz[8], ghn[8];
    float bi0 = bi[lane], bi1 = bi[64 + lane], bi2 = bi[128 + lane];
    float bh0 = bh[lane], bh1 = bh[64 + lane], bh2 = bh[128 + lane];
#pragma unroll
    for (int j = 0; j < 8; ++j) {
        gir[j] = bi0; giz[j] = bi1; gin[j] = bi2;
        ghr[j] = bh0; ghz[j] = bh1; ghn[j] = bh2;
    }
    for (int i = 0; i < 64; ++i) {
        float w0 = wi[i * 192 + lane];
        float w1 = wi[i * 192 + 64 + lane];
        float w2v = wi[i * 192 + 128 + lane];
        float u0 = wh[i * 192 + lane];
        float u1 = wh[i * 192 + 64 + lane];
        float u2 = wh[i * 192 + 128 + lane];
#pragma unroll
        for (int j = 0; j < 8; ++j) {
            float mi = m_s[(wv * 8 + j) * 64 + i];
            float hi = h_s[(wv * 8 + j) * 64 + i];
            gir[j] = fmaf(mi, w0, gir[j]);
            giz[j] = fmaf(mi, w1, giz[j]);
            gin[j] = fmaf(mi, w2v, gin[j]);
            ghr[j] = fmaf(hi, u0, ghr[j]);
            ghz[j] = fmaf(hi, u1, ghz[j]);
            ghn[j] = fmaf(hi, u2, ghn[j]);
        }
    }
#pragma unroll
    for (int j = 0; j < 8; ++j) {
        int n = nbase + j;
        float rg = 1.f / (1.f + expf(-(gir[j] + ghr[j])));
        float zg = 1.f / (1.f + expf(-(giz[j] + ghz[j])));
        float ng = tanhf(gin[j] + rg * ghn[j]);
        float h = h_s[(wv * 8 + j) * 64 + lane];
        out[(size_t)n * 64 + lane] = (1.f - zg) * ng + zg * h;
    }
}

// Set2Set LSTM cell
__global__ __launch_bounds__(256) void lstm_kernel(const float* __restrict__ q_star,
                                                   float* __restrict__ hl, float* __restrict__ cl,
                                                   const float* __restrict__ wi,
                                                   const float* __restrict__ wh,
                                                   const float* __restrict__ bi,
                                                   const float* __restrict__ bh) {
    int b = blockIdx.x;
    int j = threadIdx.x;
    __shared__ float qs[128], hs[64], g[256];
    if (j < 128) qs[j] = q_star[b * 128 + j];
    if (j < 64) hs[j] = hl[b * 64 + j];
    __syncthreads();
    float acc = bi[j] + bh[j];
#pragma unroll 8
    for (int i = 0; i < 128; ++i) acc = fmaf(qs[i], wi[i * 256 + j], acc);
#pragma unroll 8
    for (int i = 0; i < 64; ++i) acc = fmaf(hs[i], wh[i * 256 + j], acc);
    g[j] = acc;
    __syncthreads();
    if (j < 64) {
        float ig = 1.f / (1.f + expf(-g[j]));
        float fg = 1.f / (1.f + expf(-g[64 + j]));
        float gg = tanhf(g[128 + j]);
        float og = 1.f / (1.f + expf(-g[192 + j]));
        float c = fg * cl[b * 64 + j] + ig * gg;
        cl[b * 64 + j] = c;
        hl[b * 64 + j] = og * tanhf(c);
    }
}

// Set2Set attention
__global__ __launch_bounds__(256) void attn_kernel(const float* __restrict__ out,
                                                   const int* __restrict__ off_b,
                                                   const float* __restrict__ hl,
                                                   float* __restrict__ q_star,
                                                   float* __restrict__ e_ws) {
    int b = blockIdx.x;
    int start = off_b[b], end = off_b[b + 1];
    int t = threadIdx.x;
    __shared__ float q[64];
    __shared__ float red[256];
    __shared__ float racc[256];
    __shared__ float sasum[4];
    if (t < 64) q[t] = hl[b * 64 + t];
    __syncthreads();
    float lmax = -1e30f;
    for (int n = start + t; n < end; n += 256) {
        float acc = 0.f;
#pragma unroll 16
        for (int d2 = 0; d2 < 64; ++d2) acc = fmaf(out[n * 64 + d2], q[d2], acc);
        e_ws[n] = acc;
        lmax = fmaxf(lmax, acc);
    }
    red[t] = lmax;
    __syncthreads();
    for (int s2 = 128; s2 > 0; s2 >>= 1) {
        if (t < s2) red[t] = fmaxf(red[t], red[t + s2]);
        __syncthreads();
    }
    float emax = red[0];
    int w = t >> 6, d = t & 63;
    float rl = 0.f, lasum = 0.f;
    for (int n = start + w; n < end; n += 4) {
        float a = expf(e_ws[n] - emax);
        rl = fmaf(a, out[n * 64 + d], rl);
        if (d == 0) lasum += a;
    }
    racc[t] = rl;
    if (d == 0) sasum[w] = lasum;
    __syncthreads();
    if (t < 64) {
        float r = racc[t] + racc[64 + t] + racc[128 + t] + racc[192 + t];
        float as = sasum[0] + sasum[1] + sasum[2] + sasum[3];
        as = fmaxf(as, 1e-16f);
        q_star[b * 128 + t] = q[t];
        q_star[b * 128 + 64 + t] = r / as;
    }
}

// output head
__global__ __launch_bounds__(64) void head_kernel(const float* __restrict__ q_star,
                                                  const float* __restrict__ w1,
                                                  const float* __restrict__ b1,
                                                  const float* __restrict__ w2,
                                                  const float* __restrict__ b2,
                                                  float* __restrict__ y) {
    int b = blockIdx.x;
    int d = threadIdx.x;
    float qlo = q_star[b * 128 + d];
    float qhi = q_star[b * 128 + 64 + d];
    float acc = b1[d];
#pragma unroll 8
    for (int i = 0; i < 64; ++i) {
        acc = fmaf(__shfl(qlo, i, 64), w1[i * 64 + d], acc);
        acc = fmaf(__shfl(qhi, i, 64), w1[(64 + i) * 64 + d], acc);
    }
    acc = acc > 0.f ? acc : 0.f;
    float p = acc * w2[d];
    for (int off = 32; off > 0; off >>= 1) p += __shfl_down(p, off, 64);
    if (d == 0) y[b] = p + b2[0];
}

extern "C" void kernel_launch(void* const* d_in, const int* in_sizes, int n_in,
                              void* d_out, int out_size, void* d_ws, size_t ws_size,
                              hipStream_t stream) {
    (void)in_sizes; (void)n_in; (void)out_size; (void)ws_size;
    const float* x        = (const float*)d_in[0];
    const float* ea       = (const float*)d_in[1];
    const int*   eidx     = (const int*)d_in[2];
    const int*   batch    = (const int*)d_in[3];
    const float* lin0_w   = (const float*)d_in[4];
    const float* lin0_b   = (const float*)d_in[5];
    const float* mlp_w1   = (const float*)d_in[6];
    const float* mlp_b1   = (const float*)d_in[7];
    const float* mlp_w2   = (const float*)d_in[8];
    const float* mlp_b2   = (const float*)d_in[9];
    const float* conv_root= (const float*)d_in[10];
    const float* conv_bias= (const float*)d_in[11];
    const float* gru_wi   = (const float*)d_in[12];
    const float* gru_wh   = (const float*)d_in[13];
    const float* gru_bi   = (const float*)d_in[14];
    const float* gru_bh   = (const float*)d_in[15];
    const float* lstm_wi  = (const float*)d_in[16];
    const float* lstm_wh  = (const float*)d_in[17];
    const float* lstm_bi  = (const float*)d_in[18];
    const float* lstm_bh  = (const float*)d_in[19];
    const float* lin1_w   = (const float*)d_in[20];
    const float* lin1_b   = (const float*)d_in[21];
    const float* lin2_w   = (const float*)d_in[22];
    const float* lin2_b   = (const float*)d_in[23];
    float* y = (float*)d_out;

    const int* src = eidx;
    const int* dst = eidx + E_;

    char* w = (char*)d_ws;
    auto carve = [&](size_t bytes) {
        char* p = w;
        w += (bytes + 255) & ~(size_t)255;
        return p;
    };
    float* out_buf = (float*)carve((size_t)N_ * DIM_ * 4);
    float* agg     = (float*)carve((size_t)N_ * DIM_ * 4);
    float* Q       = (float*)carve((size_t)N_ * DIM_ * 4);
    float* e_ws    = (float*)carve((size_t)N_ * 4);
    int*   off_b   = (int*)carve((size_t)(B_ + 1) * 4);
    float* h1      = (float*)carve((size_t)E_ * MLP_H_ * 4);
    unsigned short* Bh = (unsigned short*)carve((size_t)PC_ * 64 * 2);
    unsigned short* Bl = (unsigned short*)carve((size_t)PC_ * 64 * 2);
    int*   src_off = (int*)carve((size_t)(N_ + 1) * 4);
    int*   eord    = (int*)carve((size_t)E_ * 4);
    // contiguous zero zone (single memset)
    char*  zero0   = w;
    float* cnt     = (float*)carve((size_t)N_ * 4);
    int*   cnt_src = (int*)carve((size_t)N_ * 4);
    int*   cur     = (int*)carve((size_t)N_ * 4);
    float* q_star  = (float*)carve((size_t)B_ * 128 * 4);
    float* hl      = (float*)carve((size_t)B_ * 64 * 4);
    float* cl      = (float*)carve((size_t)B_ * 64 * 4);
    size_t zbytes  = (size_t)(w - zero0);

    hipMemsetAsync(zero0, 0, zbytes, stream);

    lin0_kernel<<<(N_ * DIM_ + 255) / 256, 256, 0, stream>>>(x, lin0_w, lin0_b, out_buf);
    mlp1_kernel<<<(E_ * MLP_H_ + 255) / 256, 256, 0, stream>>>(ea, mlp_w1, mlp_b1, h1);
    cnt_kernel<<<(E_ + 255) / 256, 256, 0, stream>>>(dst, cnt);
    batch_off_kernel<<<1, 256, 0, stream>>>(batch, off_b);
    hist_src<<<(E_ + 255) / 256, 256, 0, stream>>>(src, cnt_src);
    scan_src<<<1, 256, 0, stream>>>(cnt_src, src_off);
    scatter_src<<<(E_ + 255) / 256, 256, 0, stream>>>(src, cur, src_off, eord);
    prep_b<<<(PC_ * 64 + 255) / 256, 256, 0, stream>>>(mlp_w2, Bh, Bl);

    for (int step = 0; step < 3; ++step) {
        q_kernel<<<(N_ + 3) / 4, 256, 0, stream>>>(out_buf, mlp_b2, Q);
        hipMemsetAsync(agg, 0, (size_t)N_ * DIM_ * 4, stream);
        msg_fused<<<N_ / GN_, 256, 0, stream>>>(out_buf, Bh, Bl, h1, Q, eord, dst,
                                                src_off, agg);
        gru_kernel<<<N_ / 32, 256, 0, stream>>>(out_buf, agg, cnt, conv_root, conv_bias,
                                                gru_wi, gru_wh, gru_bi, gru_bh);
    }

    for (int s = 0; s < 3; ++s) {
        lstm_kernel<<<B_, 256, 0, stream>>>(q_star, hl, cl, lstm_wi, lstm_wh, lstm_bi, lstm_bh);
        attn_kernel<<<B_, 256, 0, stream>>>(out_buf, off_b, hl, q_star, e_ws);
    }
    head_kernel<<<B_, 64, 0, stream>>>(q_star, lin1_w, lin1_b, lin2_w, lin2_b, y);
}

// Round 7
// 2268.627 us; speedup vs baseline: 1.1002x; 1.1002x over previous
//
#include <hip/hip_runtime.h>
#include <math.h>

// Problem dims (fixed)
#define N_ 20000
#define E_ 100000
#define B_ 128
#define F_IN_ 14
#define DIM_ 64
#define E_FEAT_ 4
#define MLP_H_ 128
#define EWC_ 4096    // DIM*DIM
#define PC_ 8192     // MLP_H * DIM (P columns)

typedef __attribute__((ext_vector_type(8))) short bf16x8;
typedef __attribute__((ext_vector_type(4))) float f32x4;

__device__ __forceinline__ unsigned short f2bf_rn(float f) {
    unsigned int u = __float_as_uint(f);
    unsigned int r = (u + 0x7fffu + ((u >> 16) & 1u)) >> 16;
    return (unsigned short)r;
}
__device__ __forceinline__ float bf2f(unsigned short h) {
    return __uint_as_float(((unsigned int)h) << 16);
}

// ---------------------------------------------------------------------------
// lin0: out[n,d] = relu(x[n,:] @ lin0_w + b)
__global__ void lin0_kernel(const float* __restrict__ x, const float* __restrict__ w,
                            const float* __restrict__ b, float* __restrict__ out) {
    int idx = blockIdx.x * blockDim.x + threadIdx.x;
    if (idx >= N_ * DIM_) return;
    int n = idx >> 6, d = idx & 63;
    float acc = b[d];
#pragma unroll
    for (int f = 0; f < F_IN_; ++f) acc = fmaf(x[n * F_IN_ + f], w[f * DIM_ + d], acc);
    out[idx] = acc > 0.f ? acc : 0.f;
}

// edge MLP layer 1, ROW-major: h1[e*128 + k] = relu(ea[e,:] @ w1 + b1)[k]
__global__ void mlp1_kernel(const float* __restrict__ ea, const float* __restrict__ w1,
                            const float* __restrict__ b1, float* __restrict__ h1) {
    int idx = blockIdx.x * blockDim.x + threadIdx.x;
    if (idx >= E_ * MLP_H_) return;
    int e = idx >> 7, k = idx & 127;
    float acc = b1[k];
#pragma unroll
    for (int f = 0; f < E_FEAT_; ++f) acc = fmaf(ea[e * E_FEAT_ + f], w1[f * MLP_H_ + k], acc);
    h1[idx] = acc > 0.f ? acc : 0.f;
}

// incoming-edge counts (float, for mean)
__global__ void cnt_kernel(const int* __restrict__ dst, float* __restrict__ cnt) {
    int e = blockIdx.x * blockDim.x + threadIdx.x;
    if (e >= E_) return;
    atomicAdd(&cnt[dst[e]], 1.0f);
}

// batch is SORTED: off_b[b] = lower_bound(batch, b). Replaces atomic histogram.
__global__ void batch_off_kernel(const int* __restrict__ batch, int* __restrict__ off_b) {
    int b = threadIdx.x;
    if (b > B_) return;
    int lo = 0, hi = N_;
    while (lo < hi) {
        int mid = (lo + hi) >> 1;
        if (batch[mid] < b) lo = mid + 1; else hi = mid;
    }
    off_b[b] = lo;
}

// src histogram for counting sort
__global__ void hist_src(const int* __restrict__ src, int* __restrict__ cnt_src) {
    int e = blockIdx.x * blockDim.x + threadIdx.x;
    if (e >= E_) return;
    atomicAdd(&cnt_src[src[e]], 1);
}

// exclusive scan over N_ bins -> src_off[0..N_]
__global__ void scan_src(const int* __restrict__ cnt_src, int* __restrict__ src_off) {
    __shared__ int part[256];
    __shared__ int off[257];
    int t = threadIdx.x;
    const int per = (N_ + 255) / 256;
    int base = t * per;
    int s = 0;
    for (int i = 0; i < per; ++i) { int b = base + i; if (b < N_) s += cnt_src[b]; }
    part[t] = s;
    __syncthreads();
    if (t == 0) {
        int a = 0;
        for (int i = 0; i < 256; ++i) { off[i] = a; a += part[i]; }
        off[256] = a;
    }
    __syncthreads();
    int run = off[t];
    for (int i = 0; i < per; ++i) {
        int b = base + i;
        if (b < N_) { src_off[b] = run; run += cnt_src[b]; }
    }
    if (t == 0) src_off[N_] = off[256];
}

// scatter edges into src-sorted order
__global__ void scatter_src(const int* __restrict__ src, int* __restrict__ cur,
                            const int* __restrict__ src_off, int* __restrict__ eord) {
    int e = blockIdx.x * blockDim.x + threadIdx.x;
    if (e >= E_) return;
    int s = src[e];
    int p = src_off[s] + atomicAdd(&cur[s], 1);
    eord[p] = e;
}

// B prep (once): Bh/Bl[c*64 + i] = bf16 hi/lo of w2[(c>>6)*4096 + i*64 + (c&63)]
__global__ void prep_b(const float* __restrict__ w2,
                       unsigned short* __restrict__ Bh,
                       unsigned short* __restrict__ Bl) {
    int idx = blockIdx.x * blockDim.x + threadIdx.x;
    if (idx >= PC_ * 64) return;
    int c = idx >> 6, i = idx & 63;
    float v = w2[(size_t)(c >> 6) * EWC_ + i * 64 + (c & 63)];
    unsigned short h = f2bf_rn(v);
    Bh[idx] = h;
    Bl[idx] = f2bf_rn(v - bf2f(h));
}

// Q[n,o] = sum_i out[n,i] * b2[i*64+o] — wave/node, b2 staged in LDS
__global__ __launch_bounds__(256) void q_kernel(const float* __restrict__ out,
                                                const float* __restrict__ b2,
                                                float* __restrict__ Q) {
    __shared__ float b2s[64 * 64];
    int tid = threadIdx.x;
#pragma unroll
    for (int it = 0; it < 4; ++it) {
        int i = it * 1024 + tid * 4;
        *(float4*)&b2s[i] = *(const float4*)&b2[i];
    }
    __syncthreads();
    int wv = __builtin_amdgcn_readfirstlane(tid >> 6);
    int n = blockIdx.x * 4 + wv;
    if (n >= N_) return;
    int o = tid & 63;
    float ov = out[(size_t)n * 64 + o];
    float acc = 0.f;
#pragma unroll 8
    for (int i = 0; i < 64; ++i) acc = fmaf(__shfl(ov, i, 64), b2s[i * 64 + o], acc);
    Q[(size_t)n * 64 + o] = acc;
}

// ---------------------------------------------------------------------------
// Fused message kernel v3. Block = 16 nodes, 4 waves, 1250 blocks.
// Per pass (<=128 edges): loop 16 k-tiles (8 k each):
//   phase A: P_s[16n][8k][64o] fp32 via split-bf16 MFMA (B streamed from L2)
//   phase B: each wave accumulates msg_s (LDS, own 32 slots) += h1 . P_s
// Epilogue: atomicAdd agg[dst] += msg_s + Q[src].  No VGPR arrays -> no spill.
#define FN_ 16
#define PSTR_ 514     // 8*64+2: node stride; 2-way-only LDS access everywhere
#define ECAP_ 128

__global__ __launch_bounds__(256) void msg_fused(const float* __restrict__ out,
                                                 const unsigned short* __restrict__ Bh,
                                                 const unsigned short* __restrict__ Bl,
                                                 const float* __restrict__ h1,
                                                 const float* __restrict__ Q,
                                                 const int* __restrict__ eord,
                                                 const int* __restrict__ dst,
                                                 const int* __restrict__ src_off,
                                                 float* __restrict__ agg) {
    __shared__ float P_s[FN_ * PSTR_];        // 32.9 KB
    __shared__ float msg_s[ECAP_ * 64];       // 32 KB
    __shared__ float h1w[ECAP_ * 8];          // 4 KB
    __shared__ int ej_s[ECAP_], ln_s[ECAP_], ds_s[ECAP_];
    __shared__ int ne_s[FN_ + 1];

    int tid = threadIdx.x;
    int lane = tid & 63;
    int wv = tid >> 6;
    int lrow = lane & 15, quad = lane >> 4;
    int nb = blockIdx.x * FN_;

    if (tid <= FN_) ne_s[tid] = src_off[nb + tid];

    // A-fragments: rows = 16 nodes, K=64, split hi/lo (loaded once)
    bf16x8 ah[2], al[2];
#pragma unroll
    for (int ks = 0; ks < 2; ++ks) {
        const float* ap = &out[(size_t)(nb + lrow) * 64 + ks * 32 + quad * 8];
        float4 v0 = *(const float4*)ap;
        float4 v1 = *(const float4*)(ap + 4);
        float v[8] = {v0.x, v0.y, v0.z, v0.w, v1.x, v1.y, v1.z, v1.w};
#pragma unroll
        for (int i = 0; i < 8; ++i) {
            unsigned short hh = f2bf_rn(v[i]);
            ah[ks][i] = (short)hh;
            al[ks][i] = (short)f2bf_rn(v[i] - bf2f(hh));
        }
    }
    __syncthreads();

    int beg = ne_s[0], end2 = ne_s[FN_];
    int bcnt = end2 - beg;
    int npass = (bcnt + ECAP_ - 1) >> 7;

    for (int pass = 0; pass < npass; ++pass) {
        // stage edge meta
        if (tid < ECAP_) {
            int pos = beg + pass * ECAP_ + tid;
            int ej = -1, lnv = -1, dv = 0;
            if (pos < end2) {
                ej = eord[pos];
                dv = dst[ej];
                int i = 0;
                while (pos >= ne_s[i + 1]) ++i;
                lnv = i;
            }
            ej_s[tid] = ej; ln_s[tid] = lnv; ds_s[tid] = dv;
        }
        // zero msg accumulators
#pragma unroll
        for (int i = tid * 4; i < ECAP_ * 64; i += 1024)
            *(float4*)&msg_s[i] = (float4){0.f, 0.f, 0.f, 0.f};
        __syncthreads();

#pragma unroll 1
        for (int t = 0; t < 16; ++t) {
            // ---- phase A: P k-tile [t*8, t*8+8) ----
#pragma unroll
            for (int f = 0; f < 8; ++f) {
                int coff = (wv * 8 + f) * 16 + lrow;     // 0..511
                int c = t * 512 + coff;                  // global P column
                f32x4 pa = {0.f, 0.f, 0.f, 0.f};
#pragma unroll
                for (int ks = 0; ks < 2; ++ks) {
                    bf16x8 bhv = *(const bf16x8*)&Bh[(size_t)c * 64 + ks * 32 + quad * 8];
                    bf16x8 blv = *(const bf16x8*)&Bl[(size_t)c * 64 + ks * 32 + quad * 8];
                    pa = __builtin_amdgcn_mfma_f32_16x16x32_bf16(ah[ks], bhv, pa, 0, 0, 0);
                    pa = __builtin_amdgcn_mfma_f32_16x16x32_bf16(al[ks], bhv, pa, 0, 0, 0);
                    pa = __builtin_amdgcn_mfma_f32_16x16x32_bf16(ah[ks], blv, pa, 0, 0, 0);
                }
                int kk = coff >> 6, o = coff & 63;
#pragma unroll
                for (int r = 0; r < 4; ++r)
                    P_s[(quad * 4 + r) * PSTR_ + kk * 64 + o] = pa[r];
            }
            // stage h1 slices: thread -> (slot = tid>>1, half = tid&1), 16B each
            {
                int slot = tid >> 1, half = tid & 1;
                int ej = ej_s[slot];
                float4 hv = {0.f, 0.f, 0.f, 0.f};
                if (ej >= 0) hv = *(const float4*)&h1[(size_t)ej * 128 + t * 8 + half * 4];
                *(float4*)&h1w[slot * 8 + half * 4] = hv;
            }
            __syncthreads();
            // ---- phase B: wave accumulates its 32 slots ----
            {
                float pv[8];
                int cur = -1;
#pragma unroll 1
                for (int j = 0; j < 32; ++j) {
                    int slot = wv * 32 + j;
                    int lnj = ln_s[slot];
                    if (lnj < 0) break;
                    if (lnj != cur) {
                        cur = lnj;
#pragma unroll
                        for (int kk = 0; kk < 8; ++kk)
                            pv[kk] = P_s[lnj * PSTR_ + kk * 64 + lane];
                    }
                    float4 hA = *(const float4*)&h1w[slot * 8];
                    float4 hB = *(const float4*)&h1w[slot * 8 + 4];
                    float s = pv[0] * hA.x;
                    s = fmaf(pv[1], hA.y, s);
                    s = fmaf(pv[2], hA.z, s);
                    s = fmaf(pv[3], hA.w, s);
                    s = fmaf(pv[4], hB.x, s);
                    s = fmaf(pv[5], hB.y, s);
                    s = fmaf(pv[6], hB.z, s);
                    s = fmaf(pv[7], hB.w, s);
                    msg_s[slot * 64 + lane] += s;
                }
            }
            __syncthreads();
        }
        // epilogue: agg[dst] += msg + Q[src]
#pragma unroll 1
        for (int j = 0; j < 32; ++j) {
            int slot = wv * 32 + j;
            int lnj = ln_s[slot];
            if (lnj < 0) break;
            float qv = Q[(size_t)(nb + lnj) * 64 + lane];
            atomicAdd(&agg[(size_t)ds_s[slot] * 64 + lane], msg_s[slot * 64 + lane] + qv);
        }
        __syncthreads();
    }
}

// combine (scatter-mean + root + bias + relu) and GRU cell; 32 nodes/block,
// 8 nodes/wave register tiling, root/h/m staged in LDS, weights streamed (L2).
__global__ __launch_bounds__(256) void gru_kernel(float* __restrict__ out,
                                                  const float* __restrict__ agg,
                                                  const float* __restrict__ cnt,
                                                  const float* __restrict__ root,
                                                  const float* __restrict__ cbias,
                                                  const float* __restrict__ wi,
                                                  const float* __restrict__ wh,
                                                  const float* __restrict__ bi,
                                                  const float* __restrict__ bh) {
    __shared__ float root_s[64 * 64];
    __shared__ float h_s[32 * 64];
    __shared__ float m_s[32 * 64];
    int tid = threadIdx.x;
    int lane = tid & 63;
    int wv = __builtin_amdgcn_readfirstlane(tid >> 6);
    int nb = blockIdx.x * 32;
#pragma unroll
    for (int it = 0; it < 4; ++it) {
        int i = it * 1024 + tid * 4;
        *(float4*)&root_s[i] = *(const float4*)&root[i];
    }
#pragma unroll
    for (int it = 0; it < 2; ++it) {
        int i = it * 1024 + tid * 4;
        *(float4*)&h_s[i] = *(const float4*)&out[(size_t)nb * 64 + i];
    }
    __syncthreads();

    int nbase = nb + wv * 8;
    float a[8];
#pragma unroll
    for (int j = 0; j < 8; ++j) {
        int n = nbase + j;
        float c = cnt[n]; c = c > 1.f ? c : 1.f;
        a[j] = agg[(size_t)n * 64 + lane] / c + cbias[lane];
    }
    for (int i = 0; i < 64; ++i) {
        float rv = root_s[i * 64 + lane];
#pragma unroll
        for (int j = 0; j < 8; ++j)
            a[j] = fmaf(h_s[(wv * 8 + j) * 64 + i], rv, a[j]);
    }
#pragma unroll
    for (int j = 0; j < 8; ++j) {
        float m = a[j] > 0.f ? a[j] : 0.f;
        m_s[(wv * 8 + j) * 64 + lane] = m;
    }
    __syncthreads();

    float gir[8], giz[8], gin[8], ghr[8], ghz[8], ghn[8];
    float bi0 = bi[lane], bi1 = bi[64 + lane], bi2 = bi[128 + lane];
    float bh0 = bh[lane], bh1 = bh[64 + lane], bh2 = bh[128 + lane];
#pragma unroll
    for (int j = 0; j < 8; ++j) {
        gir[j] = bi0; giz[j] = bi1; gin[j] = bi2;
        ghr[j] = bh0; ghz[j] = bh1; ghn[j] = bh2;
    }
    for (int i = 0; i < 64; ++i) {
        float w0 = wi[i * 192 + lane];
        float w1 = wi[i * 192 + 64 + lane];
        float w2v = wi[i * 192 + 128 + lane];
        float u0 = wh[i * 192 + lane];
        float u1 = wh[i * 192 + 64 + lane];
        float u2 = wh[i * 192 + 128 + lane];
#pragma unroll
        for (int j = 0; j < 8; ++j) {
            float mi = m_s[(wv * 8 + j) * 64 + i];
            float hi = h_s[(wv * 8 + j) * 64 + i];
            gir[j] = fmaf(mi, w0, gir[j]);
            giz[j] = fmaf(mi, w1, giz[j]);
            gin[j] = fmaf(mi, w2v, gin[j]);
            ghr[j] = fmaf(hi, u0, ghr[j]);
            ghz[j] = fmaf(hi, u1, ghz[j]);
            ghn[j] = fmaf(hi, u2, ghn[j]);
        }
    }
#pragma unroll
    for (int j = 0; j < 8; ++j) {
        int n = nbase + j;
        float rg = 1.f / (1.f + expf(-(gir[j] + ghr[j])));
        float zg = 1.f / (1.f + expf(-(giz[j] + ghz[j])));
        float ng = tanhf(gin[j] + rg * ghn[j]);
        float h = h_s[(wv * 8 + j) * 64 + lane];
        out[(size_t)n * 64 + lane] = (1.f - zg) * ng + zg * h;
    }
}

// Set2Set LSTM cell
__global__ __launch_bounds__(256) void lstm_kernel(const float* __restrict__ q_star,
                                                   float* __restrict__ hl, float* __restrict__ cl,
                                                   const float* __restrict__ wi,
                                                   const float* __restrict__ wh,
                                                   const float* __restrict__ bi,
                                                   const float* __restrict__ bh) {
    int b = blockIdx.x;
    int j = threadIdx.x;
    __shared__ float qs[128], hs[64], g[256];
    if (j < 128) qs[j] = q_star[b * 128 + j];
    if (j < 64) hs[j] = hl[b * 64 + j];
    __syncthreads();
    float acc = bi[j] + bh[j];
#pragma unroll 8
    for (int i = 0; i < 128; ++i) acc = fmaf(qs[i], wi[i * 256 + j], acc);
#pragma unroll 8
    for (int i = 0; i < 64; ++i) acc = fmaf(hs[i], wh[i * 256 + j], acc);
    g[j] = acc;
    __syncthreads();
    if (j < 64) {
        float ig = 1.f / (1.f + expf(-g[j]));
        float fg = 1.f / (1.f + expf(-g[64 + j]));
        float gg = tanhf(g[128 + j]);
        float og = 1.f / (1.f + expf(-g[192 + j]));
        float c = fg * cl[b * 64 + j] + ig * gg;
        cl[b * 64 + j] = c;
        hl[b * 64 + j] = og * tanhf(c);
    }
}

// Set2Set attention
__global__ __launch_bounds__(256) void attn_kernel(const float* __restrict__ out,
                                                   const int* __restrict__ off_b,
                                                   const float* __restrict__ hl,
                                                   float* __restrict__ q_star,
                                                   float* __restrict__ e_ws) {
    int b = blockIdx.x;
    int start = off_b[b], end = off_b[b + 1];
    int t = threadIdx.x;
    __shared__ float q[64];
    __shared__ float red[256];
    __shared__ float racc[256];
    __shared__ float sasum[4];
    if (t < 64) q[t] = hl[b * 64 + t];
    __syncthreads();
    float lmax = -1e30f;
    for (int n = start + t; n < end; n += 256) {
        float acc = 0.f;
#pragma unroll 16
        for (int d2 = 0; d2 < 64; ++d2) acc = fmaf(out[n * 64 + d2], q[d2], acc);
        e_ws[n] = acc;
        lmax = fmaxf(lmax, acc);
    }
    red[t] = lmax;
    __syncthreads();
    for (int s2 = 128; s2 > 0; s2 >>= 1) {
        if (t < s2) red[t] = fmaxf(red[t], red[t + s2]);
        __syncthreads();
    }
    float emax = red[0];
    int w = t >> 6, d = t & 63;
    float rl = 0.f, lasum = 0.f;
    for (int n = start + w; n < end; n += 4) {
        float a = expf(e_ws[n] - emax);
        rl = fmaf(a, out[n * 64 + d], rl);
        if (d == 0) lasum += a;
    }
    racc[t] = rl;
    if (d == 0) sasum[w] = lasum;
    __syncthreads();
    if (t < 64) {
        float r = racc[t] + racc[64 + t] + racc[128 + t] + racc[192 + t];
        float as = sasum[0] + sasum[1] + sasum[2] + sasum[3];
        as = fmaxf(as, 1e-16f);
        q_star[b * 128 + t] = q[t];
        q_star[b * 128 + 64 + t] = r / as;
    }
}

// output head
__global__ __launch_bounds__(64) void head_kernel(const float* __restrict__ q_star,
                                                  const float* __restrict__ w1,
                                                  const float* __restrict__ b1,
                                                  const float* __restrict__ w2,
                                                  const float* __restrict__ b2,
                                                  float* __restrict__ y) {
    int b = blockIdx.x;
    int d = threadIdx.x;
    float qlo = q_star[b * 128 + d];
    float qhi = q_star[b * 128 + 64 + d];
    float acc = b1[d];
#pragma unroll 8
    for (int i = 0; i < 64; ++i) {
        acc = fmaf(__shfl(qlo, i, 64), w1[i * 64 + d], acc);
        acc = fmaf(__shfl(qhi, i, 64), w1[(64 + i) * 64 + d], acc);
    }
    acc = acc > 0.f ? acc : 0.f;
    float p = acc * w2[d];
    for (int off = 32; off > 0; off >>= 1) p += __shfl_down(p, off, 64);
    if (d == 0) y[b] = p + b2[0];
}

extern "C" void kernel_launch(void* const* d_in, const int* in_sizes, int n_in,
                              void* d_out, int out_size, void* d_ws, size_t ws_size,
                              hipStream_t stream) {
    (void)in_sizes; (void)n_in; (void)out_size; (void)ws_size;
    const float* x        = (const float*)d_in[0];
    const float* ea       = (const float*)d_in[1];
    const int*   eidx     = (const int*)d_in[2];
    const int*   batch    = (const int*)d_in[3];
    const float* lin0_w   = (const float*)d_in[4];
    const float* lin0_b   = (const float*)d_in[5];
    const float* mlp_w1   = (const float*)d_in[6];
    const float* mlp_b1   = (const float*)d_in[7];
    const float* mlp_w2   = (const float*)d_in[8];
    const float* mlp_b2   = (const float*)d_in[9];
    const float* conv_root= (const float*)d_in[10];
    const float* conv_bias= (const float*)d_in[11];
    const float* gru_wi   = (const float*)d_in[12];
    const float* gru_wh   = (const float*)d_in[13];
    const float* gru_bi   = (const float*)d_in[14];
    const float* gru_bh   = (const float*)d_in[15];
    const float* lstm_wi  = (const float*)d_in[16];
    const float* lstm_wh  = (const float*)d_in[17];
    const float* lstm_bi  = (const float*)d_in[18];
    const float* lstm_bh  = (const float*)d_in[19];
    const float* lin1_w   = (const float*)d_in[20];
    const float* lin1_b   = (const float*)d_in[21];
    const float* lin2_w   = (const float*)d_in[22];
    const float* lin2_b   = (const float*)d_in[23];
    float* y = (float*)d_out;

    const int* src = eidx;
    const int* dst = eidx + E_;

    char* w = (char*)d_ws;
    auto carve = [&](size_t bytes) {
        char* p = w;
        w += (bytes + 255) & ~(size_t)255;
        return p;
    };
    float* out_buf = (float*)carve((size_t)N_ * DIM_ * 4);
    float* agg     = (float*)carve((size_t)N_ * DIM_ * 4);
    float* Q       = (float*)carve((size_t)N_ * DIM_ * 4);
    float* e_ws    = (float*)carve((size_t)N_ * 4);
    int*   off_b   = (int*)carve((size_t)(B_ + 1) * 4);
    float* h1      = (float*)carve((size_t)E_ * MLP_H_ * 4);
    unsigned short* Bh = (unsigned short*)carve((size_t)PC_ * 64 * 2);
    unsigned short* Bl = (unsigned short*)carve((size_t)PC_ * 64 * 2);
    int*   src_off = (int*)carve((size_t)(N_ + 1) * 4);
    int*   eord    = (int*)carve((size_t)E_ * 4);
    // contiguous zero zone (single memset)
    char*  zero0   = w;
    float* cnt     = (float*)carve((size_t)N_ * 4);
    int*   cnt_src = (int*)carve((size_t)N_ * 4);
    int*   cur     = (int*)carve((size_t)N_ * 4);
    float* q_star  = (float*)carve((size_t)B_ * 128 * 4);
    float* hl      = (float*)carve((size_t)B_ * 64 * 4);
    float* cl      = (float*)carve((size_t)B_ * 64 * 4);
    size_t zbytes  = (size_t)(w - zero0);

    hipMemsetAsync(zero0, 0, zbytes, stream);

    lin0_kernel<<<(N_ * DIM_ + 255) / 256, 256, 0, stream>>>(x, lin0_w, lin0_b, out_buf);
    mlp1_kernel<<<(E_ * MLP_H_ + 255) / 256, 256, 0, stream>>>(ea, mlp_w1, mlp_b1, h1);
    cnt_kernel<<<(E_ + 255) / 256, 256, 0, stream>>>(dst, cnt);
    batch_off_kernel<<<1, 256, 0, stream>>>(batch, off_b);
    hist_src<<<(E_ + 255) / 256, 256, 0, stream>>>(src, cnt_src);
    scan_src<<<1, 256, 0, stream>>>(cnt_src, src_off);
    scatter_src<<<(E_ + 255) / 256, 256, 0, stream>>>(src, cur, src_off, eord);
    prep_b<<<(PC_ * 64 + 255) / 256, 256, 0, stream>>>(mlp_w2, Bh, Bl);

    for (int step = 0; step < 3; ++step) {
        q_kernel<<<(N_ + 3) / 4, 256, 0, stream>>>(out_buf, mlp_b2, Q);
        hipMemsetAsync(agg, 0, (size_t)N_ * DIM_ * 4, stream);
        msg_fused<<<N_ / FN_, 256, 0, stream>>>(out_buf, Bh, Bl, h1, Q, eord, dst,
                                                src_off, agg);
        gru_kernel<<<N_ / 32, 256, 0, stream>>>(out_buf, agg, cnt, conv_root, conv_bias,
                                                gru_wi, gru_wh, gru_bi, gru_bh);
    }

    for (int s = 0; s < 3; ++s) {
        lstm_kernel<<<B_, 256, 0, stream>>>(q_star, hl, cl, lstm_wi, lstm_wh, lstm_bi, lstm_bh);
        attn_kernel<<<B_, 256, 0, stream>>>(out_buf, off_b, hl, q_star, e_ws);
    }
    head_kernel<<<B_, 64, 0, stream>>>(q_star, lin1_w, lin1_b, lin2_w, lin2_b, y);
}

// Round 8
// 1365.368 us; speedup vs baseline: 1.8281x; 1.6615x over previous
//
#include <hip/hip_runtime.h>
#include <math.h>

// Problem dims (fixed)
#define N_ 20000
#define E_ 100000
#define B_ 128
#define F_IN_ 14
#define DIM_ 64
#define E_FEAT_ 4
#define MLP_H_ 128
#define EWC_ 4096    // DIM*DIM
#define PC_ 8192     // MLP_H * DIM (P columns)

typedef __attribute__((ext_vector_type(8))) short bf16x8;
typedef __attribute__((ext_vector_type(4))) float f32x4;
typedef __attribute__((ext_vector_type(8))) _Float16 halfx8;

__device__ __forceinline__ unsigned short f2bf_rn(float f) {
    unsigned int u = __float_as_uint(f);
    unsigned int r = (u + 0x7fffu + ((u >> 16) & 1u)) >> 16;
    return (unsigned short)r;
}
__device__ __forceinline__ float bf2f(unsigned short h) {
    return __uint_as_float(((unsigned int)h) << 16);
}

// ---------------------------------------------------------------------------
// lin0: out[n,d] = relu(x[n,:] @ lin0_w + b)
__global__ void lin0_kernel(const float* __restrict__ x, const float* __restrict__ w,
                            const float* __restrict__ b, float* __restrict__ out) {
    int idx = blockIdx.x * blockDim.x + threadIdx.x;
    if (idx >= N_ * DIM_) return;
    int n = idx >> 6, d = idx & 63;
    float acc = b[d];
#pragma unroll
    for (int f = 0; f < F_IN_; ++f) acc = fmaf(x[n * F_IN_ + f], w[f * DIM_ + d], acc);
    out[idx] = acc > 0.f ? acc : 0.f;
}

// edge MLP layer 1, ROW-major: h1[e*128 + k] = relu(ea[e,:] @ w1 + b1)[k]
__global__ void mlp1_kernel(const float* __restrict__ ea, const float* __restrict__ w1,
                            const float* __restrict__ b1, float* __restrict__ h1) {
    int idx = blockIdx.x * blockDim.x + threadIdx.x;
    if (idx >= E_ * MLP_H_) return;
    int e = idx >> 7, k = idx & 127;
    float acc = b1[k];
#pragma unroll
    for (int f = 0; f < E_FEAT_; ++f) acc = fmaf(ea[e * E_FEAT_ + f], w1[f * MLP_H_ + k], acc);
    h1[idx] = acc > 0.f ? acc : 0.f;
}

// incoming-edge counts (float, for mean)
__global__ void cnt_kernel(const int* __restrict__ dst, float* __restrict__ cnt) {
    int e = blockIdx.x * blockDim.x + threadIdx.x;
    if (e >= E_) return;
    atomicAdd(&cnt[dst[e]], 1.0f);
}

// batch is SORTED: off_b[b] = lower_bound(batch, b). Replaces atomic histogram.
__global__ void batch_off_kernel(const int* __restrict__ batch, int* __restrict__ off_b) {
    int b = threadIdx.x;
    if (b > B_) return;
    int lo = 0, hi = N_;
    while (lo < hi) {
        int mid = (lo + hi) >> 1;
        if (batch[mid] < b) lo = mid + 1; else hi = mid;
    }
    off_b[b] = lo;
}

// src histogram for counting sort
__global__ void hist_src(const int* __restrict__ src, int* __restrict__ cnt_src) {
    int e = blockIdx.x * blockDim.x + threadIdx.x;
    if (e >= E_) return;
    atomicAdd(&cnt_src[src[e]], 1);
}

// exclusive scan over N_ bins -> src_off[0..N_]
__global__ void scan_src(const int* __restrict__ cnt_src, int* __restrict__ src_off) {
    __shared__ int part[256];
    __shared__ int off[257];
    int t = threadIdx.x;
    const int per = (N_ + 255) / 256;
    int base = t * per;
    int s = 0;
    for (int i = 0; i < per; ++i) { int b = base + i; if (b < N_) s += cnt_src[b]; }
    part[t] = s;
    __syncthreads();
    if (t == 0) {
        int a = 0;
        for (int i = 0; i < 256; ++i) { off[i] = a; a += part[i]; }
        off[256] = a;
    }
    __syncthreads();
    int run = off[t];
    for (int i = 0; i < per; ++i) {
        int b = base + i;
        if (b < N_) { src_off[b] = run; run += cnt_src[b]; }
    }
    if (t == 0) src_off[N_] = off[256];
}

// scatter edges into src-sorted order
__global__ void scatter_src(const int* __restrict__ src, int* __restrict__ cur,
                            const int* __restrict__ src_off, int* __restrict__ eord) {
    int e = blockIdx.x * blockDim.x + threadIdx.x;
    if (e >= E_) return;
    int s = src[e];
    int p = src_off[s] + atomicAdd(&cur[s], 1);
    eord[p] = e;
}

// B prep (once): Bh/Bl[c*64 + i] = bf16 hi/lo of w2[(c>>6)*4096 + i*64 + (c&63)]
__global__ void prep_b(const float* __restrict__ w2,
                       unsigned short* __restrict__ Bh,
                       unsigned short* __restrict__ Bl) {
    int idx = blockIdx.x * blockDim.x + threadIdx.x;
    if (idx >= PC_ * 64) return;
    int c = idx >> 6, i = idx & 63;
    float v = w2[(size_t)(c >> 6) * EWC_ + i * 64 + (c & 63)];
    unsigned short h = f2bf_rn(v);
    Bh[idx] = h;
    Bl[idx] = f2bf_rn(v - bf2f(h));
}

// Q[n,o] = sum_i out[n,i] * b2[i*64+o] — wave/node, b2 staged in LDS
__global__ __launch_bounds__(256) void q_kernel(const float* __restrict__ out,
                                                const float* __restrict__ b2,
                                                float* __restrict__ Q) {
    __shared__ float b2s[64 * 64];
    int tid = threadIdx.x;
#pragma unroll
    for (int it = 0; it < 4; ++it) {
        int i = it * 1024 + tid * 4;
        *(float4*)&b2s[i] = *(const float4*)&b2[i];
    }
    __syncthreads();
    int wv = __builtin_amdgcn_readfirstlane(tid >> 6);
    int n = blockIdx.x * 4 + wv;
    if (n >= N_) return;
    int o = tid & 63;
    float ov = out[(size_t)n * 64 + o];
    float acc = 0.f;
#pragma unroll 8
    for (int i = 0; i < 64; ++i) acc = fmaf(__shfl(ov, i, 64), b2s[i * 64 + o], acc);
    Q[(size_t)n * 64 + o] = acc;
}

// ---------------------------------------------------------------------------
// P GEMM via split-bf16 MFMA, fp16 OUTPUT: P16[r, c] = out[n0+r,:] @ B[64 x 8192].
// 3-term Ah*Bh + Al*Bh + Ah*Bl (exact to ~2^-18); storage rounds to fp16.
// Block = 128x128 tile, 4 waves of 64x64, one-shot K=64.
__global__ __launch_bounds__(256) void p_gemm_mfma(const float* __restrict__ out,
                                                   const unsigned short* __restrict__ Bh,
                                                   const unsigned short* __restrict__ Bl,
                                                   _Float16* __restrict__ P,
                                                   int n0, int n1) {
    int tid = threadIdx.x;
    int lane = tid & 63;
    int wid = tid >> 6;
    int wm = (wid & 1) * 64;
    int wn = (wid >> 1) * 64;
    int mloc0 = blockIdx.y * 128;
    int nbase = blockIdx.x * 128;
    int lrow = lane & 15, quad = lane >> 4;

    bf16x8 bhf[4][2], blf[4][2];
#pragma unroll
    for (int nf = 0; nf < 4; ++nf)
#pragma unroll
        for (int ks = 0; ks < 2; ++ks) {
            size_t g = (size_t)(nbase + wn + nf * 16 + lrow) * 64 + ks * 32 + quad * 8;
            bhf[nf][ks] = *(const bf16x8*)&Bh[g];
            blf[nf][ks] = *(const bf16x8*)&Bl[g];
        }

    f32x4 acc[4][4];
#pragma unroll
    for (int a = 0; a < 4; ++a)
#pragma unroll
        for (int b = 0; b < 4; ++b) acc[a][b] = (f32x4){0.f, 0.f, 0.f, 0.f};

#pragma unroll
    for (int mf = 0; mf < 4; ++mf) {
        int gm = n0 + mloc0 + wm + mf * 16 + lrow;
        bf16x8 ahf[2], alf[2];
#pragma unroll
        for (int ks = 0; ks < 2; ++ks) {
            float v[8];
            if (gm < n1) {
                float4 v0 = *(const float4*)&out[(size_t)gm * 64 + ks * 32 + quad * 8];
                float4 v1 = *(const float4*)&out[(size_t)gm * 64 + ks * 32 + quad * 8 + 4];
                v[0] = v0.x; v[1] = v0.y; v[2] = v0.z; v[3] = v0.w;
                v[4] = v1.x; v[5] = v1.y; v[6] = v1.z; v[7] = v1.w;
            } else {
#pragma unroll
                for (int i = 0; i < 8; ++i) v[i] = 0.f;
            }
#pragma unroll
            for (int i = 0; i < 8; ++i) {
                unsigned short hh = f2bf_rn(v[i]);
                ahf[ks][i] = (short)hh;
                alf[ks][i] = (short)f2bf_rn(v[i] - bf2f(hh));
            }
        }
#pragma unroll
        for (int nf = 0; nf < 4; ++nf) {
#pragma unroll
            for (int ks = 0; ks < 2; ++ks) {
                acc[mf][nf] = __builtin_amdgcn_mfma_f32_16x16x32_bf16(
                    ahf[ks], bhf[nf][ks], acc[mf][nf], 0, 0, 0);
                acc[mf][nf] = __builtin_amdgcn_mfma_f32_16x16x32_bf16(
                    alf[ks], bhf[nf][ks], acc[mf][nf], 0, 0, 0);
                acc[mf][nf] = __builtin_amdgcn_mfma_f32_16x16x32_bf16(
                    ahf[ks], blf[nf][ks], acc[mf][nf], 0, 0, 0);
            }
        }
    }

    // epilogue: C/D frag layout col=lane&15, row=quad*4+reg (m89-verified);
    // fp16 stores write-combine in L2 (adjacent nf frags fill adjacent 32B).
#pragma unroll
    for (int mf = 0; mf < 4; ++mf)
#pragma unroll
        for (int nf = 0; nf < 4; ++nf)
#pragma unroll
            for (int r = 0; r < 4; ++r) {
                int mloc = mloc0 + wm + mf * 16 + quad * 4 + r;
                if (n0 + mloc < n1)
                    P[(size_t)mloc * PC_ + nbase + wn + nf * 16 + lrow] =
                        (_Float16)acc[mf][nf][r];
            }
}

// per-edge contraction vs fp16 P, wave per src node, BW-oriented:
// lanes = (kq in [0,8)) x (og in [0,8)); per k-iter one 16B P load (wave covers
// 1KB contiguous), 8 edges in registers, h1 staged per-wave in LDS (broadcast
// reads), 3-step shfl_xor kq-reduce. No __syncthreads at all.
__global__ __launch_bounds__(256) void edge_msg(const _Float16* __restrict__ P,
                                                const float* __restrict__ h1,
                                                const float* __restrict__ Q,
                                                const int* __restrict__ eord,
                                                const int* __restrict__ dst,
                                                const int* __restrict__ src_off,
                                                float* __restrict__ agg,
                                                int n0, int n1) {
    __shared__ float h1_s[4][8 * 128];   // per-wave: 8 edges x 128 k (4 KB)
    __shared__ float red_s[4][8 * 64];   // per-wave: 8 edges x 64 o (2 KB)
    int wv = __builtin_amdgcn_readfirstlane((int)(threadIdx.x >> 6));
    int r = blockIdx.x * 4 + wv;
    int n = n0 + r;
    if (n >= n1) return;
    int lane = threadIdx.x & 63;
    int kq = lane >> 3;          // [0,8)
    int og = lane & 7;           // [0,8): o = og*8 .. og*8+7
    int beg = src_off[n], end2 = src_off[n + 1];
    if (beg == end2) return;
    const _Float16* Pr = P + (size_t)r * PC_;
    float qv = Q[(size_t)n * 64 + lane];
    float* h1w = h1_s[wv];
    float* redw = red_s[wv];
    for (int g = beg; g < end2; g += 8) {
        int gcnt = end2 - g; if (gcnt > 8) gcnt = 8;
        int dd[8];
#pragma unroll
        for (int j = 0; j < 8; ++j) dd[j] = dst[eord[g + (j < gcnt ? j : 0)]];
        // stage 8 h1 rows (coalesced float4)
#pragma unroll
        for (int t = 0; t < 4; ++t) {
            int i = t * 256 + lane * 4;
            int j = i >> 7, k = i & 127;
            int ej = eord[g + (j < gcnt ? j : 0)];
            *(float4*)&h1w[j * 128 + k] = *(const float4*)&h1[(size_t)ej * 128 + k];
        }
        float acc[8][8];
#pragma unroll
        for (int j = 0; j < 8; ++j)
#pragma unroll
            for (int c = 0; c < 8; ++c) acc[j][c] = 0.f;
#pragma unroll 4
        for (int kt = 0; kt < 16; ++kt) {
            halfx8 pv = *(const halfx8*)&Pr[(size_t)(kt * 8 + kq) * 64 + og * 8];
            float pf[8];
#pragma unroll
            for (int c = 0; c < 8; ++c) pf[c] = (float)pv[c];
#pragma unroll
            for (int j = 0; j < 8; ++j) {
                float hv = h1w[j * 128 + kt * 8 + kq];
#pragma unroll
                for (int c = 0; c < 8; ++c) acc[j][c] = fmaf(hv, pf[c], acc[j][c]);
            }
        }
        // reduce over the 8 kq groups (xor 8,16,32); kq==0 lanes hold result
#pragma unroll
        for (int j = 0; j < 8; ++j) {
#pragma unroll
            for (int c = 0; c < 8; ++c) {
                float v = acc[j][c];
                v += __shfl_xor(v, 8, 64);
                v += __shfl_xor(v, 16, 64);
                v += __shfl_xor(v, 32, 64);
                acc[j][c] = v;
            }
            if (kq == 0) {
                float4 v0 = {acc[j][0], acc[j][1], acc[j][2], acc[j][3]};
                float4 v1 = {acc[j][4], acc[j][5], acc[j][6], acc[j][7]};
                *(float4*)&redw[j * 64 + og * 8] = v0;
                *(float4*)&redw[j * 64 + og * 8 + 4] = v1;
            }
        }
        for (int j = 0; j < gcnt; ++j)
            atomicAdd(&agg[(size_t)dd[j] * 64 + lane], redw[j * 64 + lane] + qv);
    }
}

// combine (scatter-mean + root + bias + relu) and GRU cell; 32 nodes/block,
// 8 nodes/wave register tiling, root/h/m staged in LDS, weights streamed (L2).
__global__ __launch_bounds__(256) void gru_kernel(float* __restrict__ out,
                                                  const float* __restrict__ agg,
                                                  const float* __restrict__ cnt,
                                                  const float* __restrict__ root,
                                                  const float* __restrict__ cbias,
                                                  const float* __restrict__ wi,
                                                  const float* __restrict__ wh,
                                                  const float* __restrict__ bi,
                                                  const float* __restrict__ bh) {
    __shared__ float root_s[64 * 64];
    __shared__ float h_s[32 * 64];
    __shared__ float m_s[32 * 64];
    int tid = threadIdx.x;
    int lane = tid & 63;
    int wv = __builtin_amdgcn_readfirstlane(tid >> 6);
    int nb = blockIdx.x * 32;
#pragma unroll
    for (int it = 0; it < 4; ++it) {
        int i = it * 1024 + tid * 4;
        *(float4*)&root_s[i] = *(const float4*)&root[i];
    }
#pragma unroll
    for (int it = 0; it < 2; ++it) {
        int i = it * 1024 + tid * 4;
        *(float4*)&h_s[i] = *(const float4*)&out[(size_t)nb * 64 + i];
    }
    __syncthreads();

    int nbase = nb + wv * 8;
    float a[8];
#pragma unroll
    for (int j = 0; j < 8; ++j) {
        int n = nbase + j;
        float c = cnt[n]; c = c > 1.f ? c : 1.f;
        a[j] = agg[(size_t)n * 64 + lane] / c + cbias[lane];
    }
    for (int i = 0; i < 64; ++i) {
        float rv = root_s[i * 64 + lane];
#pragma unroll
        for (int j = 0; j < 8; ++j)
            a[j] = fmaf(h_s[(wv * 8 + j) * 64 + i], rv, a[j]);
    }
#pragma unroll
    for (int j = 0; j < 8; ++j) {
        float m = a[j] > 0.f ? a[j] : 0.f;
        m_s[(wv * 8 + j) * 64 + lane] = m;
    }
    __syncthreads();

    float gir[8], giz[8], gin[8], ghr[8], ghz[8], ghn[8];
    float bi0 = bi[lane], bi1 = bi[64 + lane], bi2 = bi[128 + lane];
    float bh0 = bh[lane], bh1 = bh[64 + lane], bh2 = bh[128 + lane];
#pragma unroll
    for (int j = 0; j < 8; ++j) {
        gir[j] = bi0; giz[j] = bi1; gin[j] = bi2;
        ghr[j] = bh0; ghz[j] = bh1; ghn[j] = bh2;
    }
    for (int i = 0; i < 64; ++i) {
        float w0 = wi[i * 192 + lane];
        float w1 = wi[i * 192 + 64 + lane];
        float w2v = wi[i * 192 + 128 + lane];
        float u0 = wh[i * 192 + lane];
        float u1 = wh[i * 192 + 64 + lane];
        float u2 = wh[i * 192 + 128 + lane];
#pragma unroll
        for (int j = 0; j < 8; ++j) {
            float mi = m_s[(wv * 8 + j) * 64 + i];
            float hi = h_s[(wv * 8 + j) * 64 + i];
            gir[j] = fmaf(mi, w0, gir[j]);
            giz[j] = fmaf(mi, w1, giz[j]);
            gin[j] = fmaf(mi, w2v, gin[j]);
            ghr[j] = fmaf(hi, u0, ghr[j]);
            ghz[j] = fmaf(hi, u1, ghz[j]);
            ghn[j] = fmaf(hi, u2, ghn[j]);
        }
    }
#pragma unroll
    for (int j = 0; j < 8; ++j) {
        int n = nbase + j;
        float rg = 1.f / (1.f + expf(-(gir[j] + ghr[j])));
        float zg = 1.f / (1.f + expf(-(giz[j] + ghz[j])));
        float ng = tanhf(gin[j] + rg * ghn[j]);
        float h = h_s[(wv * 8 + j) * 64 + lane];
        out[(size_t)n * 64 + lane] = (1.f - zg) * ng + zg * h;
    }
}

// Set2Set LSTM cell
__global__ __launch_bounds__(256) void lstm_kernel(const float* __restrict__ q_star,
                                                   float* __restrict__ hl, float* __restrict__ cl,
                                                   const float* __restrict__ wi,
                                                   const float* __restrict__ wh,
                                                   const float* __restrict__ bi,
                                                   const float* __restrict__ bh) {
    int b = blockIdx.x;
    int j = threadIdx.x;
    __shared__ float qs[128], hs[64], g[256];
    if (j < 128) qs[j] = q_star[b * 128 + j];
    if (j < 64) hs[j] = hl[b * 64 + j];
    __syncthreads();
    float acc = bi[j] + bh[j];
#pragma unroll 8
    for (int i = 0; i < 128; ++i) acc = fmaf(qs[i], wi[i * 256 + j], acc);
#pragma unroll 8
    for (int i = 0; i < 64; ++i) acc = fmaf(hs[i], wh[i * 256 + j], acc);
    g[j] = acc;
    __syncthreads();
    if (j < 64) {
        float ig = 1.f / (1.f + expf(-g[j]));
        float fg = 1.f / (1.f + expf(-g[64 + j]));
        float gg = tanhf(g[128 + j]);
        float og = 1.f / (1.f + expf(-g[192 + j]));
        float c = fg * cl[b * 64 + j] + ig * gg;
        cl[b * 64 + j] = c;
        hl[b * 64 + j] = og * tanhf(c);
    }
}

// Set2Set attention
__global__ __launch_bounds__(256) void attn_kernel(const float* __restrict__ out,
                                                   const int* __restrict__ off_b,
                                                   const float* __restrict__ hl,
                                                   float* __restrict__ q_star,
                                                   float* __restrict__ e_ws) {
    int b = blockIdx.x;
    int start = off_b[b], end = off_b[b + 1];
    int t = threadIdx.x;
    __shared__ float q[64];
    __shared__ float red[256];
    __shared__ float racc[256];
    __shared__ float sasum[4];
    if (t < 64) q[t] = hl[b * 64 + t];
    __syncthreads();
    float lmax = -1e30f;
    for (int n = start + t; n < end; n += 256) {
        float acc = 0.f;
#pragma unroll 16
        for (int d2 = 0; d2 < 64; ++d2) acc = fmaf(out[n * 64 + d2], q[d2], acc);
        e_ws[n] = acc;
        lmax = fmaxf(lmax, acc);
    }
    red[t] = lmax;
    __syncthreads();
    for (int s2 = 128; s2 > 0; s2 >>= 1) {
        if (t < s2) red[t] = fmaxf(red[t], red[t + s2]);
        __syncthreads();
    }
    float emax = red[0];
    int w = t >> 6, d = t & 63;
    float rl = 0.f, lasum = 0.f;
    for (int n = start + w; n < end; n += 4) {
        float a = expf(e_ws[n] - emax);
        rl = fmaf(a, out[n * 64 + d], rl);
        if (d == 0) lasum += a;
    }
    racc[t] = rl;
    if (d == 0) sasum[w] = lasum;
    __syncthreads();
    if (t < 64) {
        float r = racc[t] + racc[64 + t] + racc[128 + t] + racc[192 + t];
        float as = sasum[0] + sasum[1] + sasum[2] + sasum[3];
        as = fmaxf(as, 1e-16f);
        q_star[b * 128 + t] = q[t];
        q_star[b * 128 + 64 + t] = r / as;
    }
}

// output head
__global__ __launch_bounds__(64) void head_kernel(const float* __restrict__ q_star,
                                                  const float* __restrict__ w1,
                                                  const float* __restrict__ b1,
                                                  const float* __restrict__ w2,
                                                  const float* __restrict__ b2,
                                                  float* __restrict__ y) {
    int b = blockIdx.x;
    int d = threadIdx.x;
    float qlo = q_star[b * 128 + d];
    float qhi = q_star[b * 128 + 64 + d];
    float acc = b1[d];
#pragma unroll 8
    for (int i = 0; i < 64; ++i) {
        acc = fmaf(__shfl(qlo, i, 64), w1[i * 64 + d], acc);
        acc = fmaf(__shfl(qhi, i, 64), w1[(64 + i) * 64 + d], acc);
    }
    acc = acc > 0.f ? acc : 0.f;
    float p = acc * w2[d];
    for (int off = 32; off > 0; off >>= 1) p += __shfl_down(p, off, 64);
    if (d == 0) y[b] = p + b2[0];
}

extern "C" void kernel_launch(void* const* d_in, const int* in_sizes, int n_in,
                              void* d_out, int out_size, void* d_ws, size_t ws_size,
                              hipStream_t stream) {
    (void)in_sizes; (void)n_in; (void)out_size;
    const float* x        = (const float*)d_in[0];
    const float* ea       = (const float*)d_in[1];
    const int*   eidx     = (const int*)d_in[2];
    const int*   batch    = (const int*)d_in[3];
    const float* lin0_w   = (const float*)d_in[4];
    const float* lin0_b   = (const float*)d_in[5];
    const float* mlp_w1   = (const float*)d_in[6];
    const float* mlp_b1   = (const float*)d_in[7];
    const float* mlp_w2   = (const float*)d_in[8];
    const float* mlp_b2   = (const float*)d_in[9];
    const float* conv_root= (const float*)d_in[10];
    const float* conv_bias= (const float*)d_in[11];
    const float* gru_wi   = (const float*)d_in[12];
    const float* gru_wh   = (const float*)d_in[13];
    const float* gru_bi   = (const float*)d_in[14];
    const float* gru_bh   = (const float*)d_in[15];
    const float* lstm_wi  = (const float*)d_in[16];
    const float* lstm_wh  = (const float*)d_in[17];
    const float* lstm_bi  = (const float*)d_in[18];
    const float* lstm_bh  = (const float*)d_in[19];
    const float* lin1_w   = (const float*)d_in[20];
    const float* lin1_b   = (const float*)d_in[21];
    const float* lin2_w   = (const float*)d_in[22];
    const float* lin2_b   = (const float*)d_in[23];
    float* y = (float*)d_out;

    const int* src = eidx;
    const int* dst = eidx + E_;

    char* w = (char*)d_ws;
    auto carve = [&](size_t bytes) {
        char* p = w;
        w += (bytes + 255) & ~(size_t)255;
        return p;
    };
    float* out_buf = (float*)carve((size_t)N_ * DIM_ * 4);
    float* agg     = (float*)carve((size_t)N_ * DIM_ * 4);
    float* Q       = (float*)carve((size_t)N_ * DIM_ * 4);
    float* e_ws    = (float*)carve((size_t)N_ * 4);
    int*   off_b   = (int*)carve((size_t)(B_ + 1) * 4);
    float* h1      = (float*)carve((size_t)E_ * MLP_H_ * 4);
    unsigned short* Bh = (unsigned short*)carve((size_t)PC_ * 64 * 2);
    unsigned short* Bl = (unsigned short*)carve((size_t)PC_ * 64 * 2);
    int*   src_off = (int*)carve((size_t)(N_ + 1) * 4);
    int*   eord    = (int*)carve((size_t)E_ * 4);
    // contiguous zero zone (single memset)
    char*  zero0   = w;
    float* cnt     = (float*)carve((size_t)N_ * 4);
    int*   cnt_src = (int*)carve((size_t)N_ * 4);
    int*   cur     = (int*)carve((size_t)N_ * 4);
    float* q_star  = (float*)carve((size_t)B_ * 128 * 4);
    float* hl      = (float*)carve((size_t)B_ * 64 * 4);
    float* cl      = (float*)carve((size_t)B_ * 64 * 4);
    size_t zbytes  = (size_t)(w - zero0);

    size_t used = (size_t)(w - (char*)d_ws);
    _Float16* P = (_Float16*)w;
    size_t avail = ws_size > used ? ws_size - used : 0;
    long long nc = (long long)(avail / ((size_t)PC_ * 2));   // fp16 P rows
    if (nc > N_) nc = N_;
    nc &= ~127LL;
    if (nc < 128) nc = 128;
    int NC = (int)nc;

    hipMemsetAsync(zero0, 0, zbytes, stream);

    lin0_kernel<<<(N_ * DIM_ + 255) / 256, 256, 0, stream>>>(x, lin0_w, lin0_b, out_buf);
    mlp1_kernel<<<(E_ * MLP_H_ + 255) / 256, 256, 0, stream>>>(ea, mlp_w1, mlp_b1, h1);
    cnt_kernel<<<(E_ + 255) / 256, 256, 0, stream>>>(dst, cnt);
    batch_off_kernel<<<1, 256, 0, stream>>>(batch, off_b);
    hist_src<<<(E_ + 255) / 256, 256, 0, stream>>>(src, cnt_src);
    scan_src<<<1, 256, 0, stream>>>(cnt_src, src_off);
    scatter_src<<<(E_ + 255) / 256, 256, 0, stream>>>(src, cur, src_off, eord);
    prep_b<<<(PC_ * 64 + 255) / 256, 256, 0, stream>>>(mlp_w2, Bh, Bl);

    for (int step = 0; step < 3; ++step) {
        q_kernel<<<(N_ + 3) / 4, 256, 0, stream>>>(out_buf, mlp_b2, Q);
        hipMemsetAsync(agg, 0, (size_t)N_ * DIM_ * 4, stream);
        for (int n0 = 0; n0 < N_; n0 += NC) {
            int n1 = n0 + NC < N_ ? n0 + NC : N_;
            dim3 g(PC_ / 128, (n1 - n0 + 127) / 128);
            p_gemm_mfma<<<g, 256, 0, stream>>>(out_buf, Bh, Bl, P, n0, n1);
            int nn = n1 - n0;
            edge_msg<<<(nn + 3) / 4, 256, 0, stream>>>(P, h1, Q, eord, dst,
                                                       src_off, agg, n0, n1);
        }
        gru_kernel<<<N_ / 32, 256, 0, stream>>>(out_buf, agg, cnt, conv_root, conv_bias,
                                                gru_wi, gru_wh, gru_bi, gru_bh);
    }

    for (int s = 0; s < 3; ++s) {
        lstm_kernel<<<B_, 256, 0, stream>>>(q_star, hl, cl, lstm_wi, lstm_wh, lstm_bi, lstm_bh);
        attn_kernel<<<B_, 256, 0, stream>>>(out_buf, off_b, hl, q_star, e_ws);
    }
    head_kernel<<<B_, 64, 0, stream>>>(q_star, lin1_w, lin1_b, lin2_w, lin2_b, y);
}

// Round 9
// 1317.875 us; speedup vs baseline: 1.8940x; 1.0360x over previous
//
#include <hip/hip_runtime.h>
#include <math.h>

// Problem dims (fixed)
#define N_ 20000
#define E_ 100000
#define B_ 128
#define F_IN_ 14
#define DIM_ 64
#define E_FEAT_ 4
#define MLP_H_ 128
#define EWC_ 4096    // DIM*DIM
#define PC_ 8192     // MLP_H * DIM (P columns)

typedef __attribute__((ext_vector_type(8))) short bf16x8;
typedef __attribute__((ext_vector_type(4))) float f32x4;
typedef __attribute__((ext_vector_type(8))) _Float16 halfx8;

__device__ __forceinline__ unsigned short f2bf_rn(float f) {
    unsigned int u = __float_as_uint(f);
    unsigned int r = (u + 0x7fffu + ((u >> 16) & 1u)) >> 16;
    return (unsigned short)r;
}
__device__ __forceinline__ float bf2f(unsigned short h) {
    return __uint_as_float(((unsigned int)h) << 16);
}

// ---------------------------------------------------------------------------
// lin0: out[n,d] = relu(x[n,:] @ lin0_w + b)
__global__ void lin0_kernel(const float* __restrict__ x, const float* __restrict__ w,
                            const float* __restrict__ b, float* __restrict__ out) {
    int idx = blockIdx.x * blockDim.x + threadIdx.x;
    if (idx >= N_ * DIM_) return;
    int n = idx >> 6, d = idx & 63;
    float acc = b[d];
#pragma unroll
    for (int f = 0; f < F_IN_; ++f) acc = fmaf(x[n * F_IN_ + f], w[f * DIM_ + d], acc);
    out[idx] = acc > 0.f ? acc : 0.f;
}

// edge MLP layer 1, ROW-major: h1[e*128 + k] = relu(ea[e,:] @ w1 + b1)[k]
__global__ void mlp1_kernel(const float* __restrict__ ea, const float* __restrict__ w1,
                            const float* __restrict__ b1, float* __restrict__ h1) {
    int idx = blockIdx.x * blockDim.x + threadIdx.x;
    if (idx >= E_ * MLP_H_) return;
    int e = idx >> 7, k = idx & 127;
    float acc = b1[k];
#pragma unroll
    for (int f = 0; f < E_FEAT_; ++f) acc = fmaf(ea[e * E_FEAT_ + f], w1[f * MLP_H_ + k], acc);
    h1[idx] = acc > 0.f ? acc : 0.f;
}

// incoming-edge counts (float, for mean)
__global__ void cnt_kernel(const int* __restrict__ dst, float* __restrict__ cnt) {
    int e = blockIdx.x * blockDim.x + threadIdx.x;
    if (e >= E_) return;
    atomicAdd(&cnt[dst[e]], 1.0f);
}

// batch is SORTED: off_b[b] = lower_bound(batch, b). Replaces atomic histogram.
__global__ void batch_off_kernel(const int* __restrict__ batch, int* __restrict__ off_b) {
    int b = threadIdx.x;
    if (b > B_) return;
    int lo = 0, hi = N_;
    while (lo < hi) {
        int mid = (lo + hi) >> 1;
        if (batch[mid] < b) lo = mid + 1; else hi = mid;
    }
    off_b[b] = lo;
}

// src histogram for counting sort
__global__ void hist_src(const int* __restrict__ src, int* __restrict__ cnt_src) {
    int e = blockIdx.x * blockDim.x + threadIdx.x;
    if (e >= E_) return;
    atomicAdd(&cnt_src[src[e]], 1);
}

// exclusive scan over N_ bins -> src_off[0..N_]
__global__ void scan_src(const int* __restrict__ cnt_src, int* __restrict__ src_off) {
    __shared__ int part[256];
    __shared__ int off[257];
    int t = threadIdx.x;
    const int per = (N_ + 255) / 256;
    int base = t * per;
    int s = 0;
    for (int i = 0; i < per; ++i) { int b = base + i; if (b < N_) s += cnt_src[b]; }
    part[t] = s;
    __syncthreads();
    if (t == 0) {
        int a = 0;
        for (int i = 0; i < 256; ++i) { off[i] = a; a += part[i]; }
        off[256] = a;
    }
    __syncthreads();
    int run = off[t];
    for (int i = 0; i < per; ++i) {
        int b = base + i;
        if (b < N_) { src_off[b] = run; run += cnt_src[b]; }
    }
    if (t == 0) src_off[N_] = off[256];
}

// scatter edges into src-sorted order
__global__ void scatter_src(const int* __restrict__ src, int* __restrict__ cur,
                            const int* __restrict__ src_off, int* __restrict__ eord) {
    int e = blockIdx.x * blockDim.x + threadIdx.x;
    if (e >= E_) return;
    int s = src[e];
    int p = src_off[s] + atomicAdd(&cur[s], 1);
    eord[p] = e;
}

// B prep (once): Bh/Bl[c*64 + i] = bf16 hi/lo of w2[(c>>6)*4096 + i*64 + (c&63)]
__global__ void prep_b(const float* __restrict__ w2,
                       unsigned short* __restrict__ Bh,
                       unsigned short* __restrict__ Bl) {
    int idx = blockIdx.x * blockDim.x + threadIdx.x;
    if (idx >= PC_ * 64) return;
    int c = idx >> 6, i = idx & 63;
    float v = w2[(size_t)(c >> 6) * EWC_ + i * 64 + (c & 63)];
    unsigned short h = f2bf_rn(v);
    Bh[idx] = h;
    Bl[idx] = f2bf_rn(v - bf2f(h));
}

// Q[n,o] = sum_i out[n,i] * b2[i*64+o] — wave/node, b2 staged in LDS
__global__ __launch_bounds__(256) void q_kernel(const float* __restrict__ out,
                                                const float* __restrict__ b2,
                                                float* __restrict__ Q) {
    __shared__ float b2s[64 * 64];
    int tid = threadIdx.x;
#pragma unroll
    for (int it = 0; it < 4; ++it) {
        int i = it * 1024 + tid * 4;
        *(float4*)&b2s[i] = *(const float4*)&b2[i];
    }
    __syncthreads();
    int wv = __builtin_amdgcn_readfirstlane(tid >> 6);
    int n = blockIdx.x * 4 + wv;
    if (n >= N_) return;
    int o = tid & 63;
    float ov = out[(size_t)n * 64 + o];
    float acc = 0.f;
#pragma unroll 8
    for (int i = 0; i < 64; ++i) acc = fmaf(__shfl(ov, i, 64), b2s[i * 64 + o], acc);
    Q[(size_t)n * 64 + o] = acc;
}

// ---------------------------------------------------------------------------
// P GEMM via split-bf16 MFMA, fp16 OUTPUT: P16[r, c] = out[n0+r,:] @ B[64 x 8192].
// 3-term Ah*Bh + Al*Bh + Ah*Bl; storage rounds to fp16.
// Block = 128x128 tile, 4 waves of 64x64, one-shot K=64.
// Epilogue staged through LDS -> fully-coalesced dwordx4 stores (256B/row-seg).
#define STSTR_ 136   // fp16 elems per staged row (272B; 16B-aligned, 2-way banks)
__global__ __launch_bounds__(256) void p_gemm_mfma(const float* __restrict__ out,
                                                   const unsigned short* __restrict__ Bh,
                                                   const unsigned short* __restrict__ Bl,
                                                   _Float16* __restrict__ P,
                                                   int n0, int n1) {
    __shared__ _Float16 st[128 * STSTR_];   // 34.8 KB
    int tid = threadIdx.x;
    int lane = tid & 63;
    int wid = tid >> 6;
    int wm = (wid & 1) * 64;
    int wn = (wid >> 1) * 64;
    int mloc0 = blockIdx.y * 128;
    int nbase = blockIdx.x * 128;
    int lrow = lane & 15, quad = lane >> 4;

    bf16x8 bhf[4][2], blf[4][2];
#pragma unroll
    for (int nf = 0; nf < 4; ++nf)
#pragma unroll
        for (int ks = 0; ks < 2; ++ks) {
            size_t g = (size_t)(nbase + wn + nf * 16 + lrow) * 64 + ks * 32 + quad * 8;
            bhf[nf][ks] = *(const bf16x8*)&Bh[g];
            blf[nf][ks] = *(const bf16x8*)&Bl[g];
        }

    f32x4 acc[4][4];
#pragma unroll
    for (int a = 0; a < 4; ++a)
#pragma unroll
        for (int b = 0; b < 4; ++b) acc[a][b] = (f32x4){0.f, 0.f, 0.f, 0.f};

#pragma unroll
    for (int mf = 0; mf < 4; ++mf) {
        int gm = n0 + mloc0 + wm + mf * 16 + lrow;
        bf16x8 ahf[2], alf[2];
#pragma unroll
        for (int ks = 0; ks < 2; ++ks) {
            float v[8];
            if (gm < n1) {
                float4 v0 = *(const float4*)&out[(size_t)gm * 64 + ks * 32 + quad * 8];
                float4 v1 = *(const float4*)&out[(size_t)gm * 64 + ks * 32 + quad * 8 + 4];
                v[0] = v0.x; v[1] = v0.y; v[2] = v0.z; v[3] = v0.w;
                v[4] = v1.x; v[5] = v1.y; v[6] = v1.z; v[7] = v1.w;
            } else {
#pragma unroll
                for (int i = 0; i < 8; ++i) v[i] = 0.f;
            }
#pragma unroll
            for (int i = 0; i < 8; ++i) {
                unsigned short hh = f2bf_rn(v[i]);
                ahf[ks][i] = (short)hh;
                alf[ks][i] = (short)f2bf_rn(v[i] - bf2f(hh));
            }
        }
#pragma unroll
        for (int nf = 0; nf < 4; ++nf) {
#pragma unroll
            for (int ks = 0; ks < 2; ++ks) {
                acc[mf][nf] = __builtin_amdgcn_mfma_f32_16x16x32_bf16(
                    ahf[ks], bhf[nf][ks], acc[mf][nf], 0, 0, 0);
                acc[mf][nf] = __builtin_amdgcn_mfma_f32_16x16x32_bf16(
                    alf[ks], bhf[nf][ks], acc[mf][nf], 0, 0, 0);
                acc[mf][nf] = __builtin_amdgcn_mfma_f32_16x16x32_bf16(
                    ahf[ks], blf[nf][ks], acc[mf][nf], 0, 0, 0);
            }
        }
    }

    // stage tile in LDS (C/D frag layout col=lane&15, row=quad*4+reg; m89-verified)
#pragma unroll
    for (int mf = 0; mf < 4; ++mf)
#pragma unroll
        for (int nf = 0; nf < 4; ++nf)
#pragma unroll
            for (int r = 0; r < 4; ++r) {
                int row = wm + mf * 16 + quad * 4 + r;
                int col = wn + nf * 16 + lrow;
                st[row * STSTR_ + col] = (_Float16)acc[mf][nf][r];
            }
    __syncthreads();
    // coalesced write-out: 16 lanes cover one 256B row segment
#pragma unroll
    for (int it = 0; it < 8; ++it) {
        int chunk = it * 256 + tid;          // 2048 chunks of 8 fp16
        int row = chunk >> 4;
        int cb = (chunk & 15) * 8;
        if (n0 + mloc0 + row < n1) {
            int4 v = *(const int4*)&st[row * STSTR_ + cb];
            *(int4*)&P[(size_t)(mloc0 + row) * PC_ + nbase + cb] = v;
        }
    }
}

// per-edge contraction vs fp16 P, wave per src node, BW-oriented:
// lanes = (kq in [0,8)) x (og in [0,8)); per k-iter one 16B P load (wave covers
// 1KB contiguous), 8 edges in registers, h1 staged per-wave in LDS (broadcast
// reads), 3-step shfl_xor kq-reduce. No __syncthreads at all.
__global__ __launch_bounds__(256) void edge_msg(const _Float16* __restrict__ P,
                                                const float* __restrict__ h1,
                                                const float* __restrict__ Q,
                                                const int* __restrict__ eord,
                                                const int* __restrict__ dst,
                                                const int* __restrict__ src_off,
                                                float* __restrict__ agg,
                                                int n0, int n1) {
    __shared__ float h1_s[4][8 * 128];   // per-wave: 8 edges x 128 k (4 KB)
    __shared__ float red_s[4][8 * 64];   // per-wave: 8 edges x 64 o (2 KB)
    int wv = __builtin_amdgcn_readfirstlane((int)(threadIdx.x >> 6));
    int r = blockIdx.x * 4 + wv;
    int n = n0 + r;
    if (n >= n1) return;
    int lane = threadIdx.x & 63;
    int kq = lane >> 3;          // [0,8)
    int og = lane & 7;           // [0,8): o = og*8 .. og*8+7
    int beg = src_off[n], end2 = src_off[n + 1];
    if (beg == end2) return;
    const _Float16* Pr = P + (size_t)r * PC_;
    float qv = Q[(size_t)n * 64 + lane];
    float* h1w = h1_s[wv];
    float* redw = red_s[wv];
    for (int g = beg; g < end2; g += 8) {
        int gcnt = end2 - g; if (gcnt > 8) gcnt = 8;
        int dd[8];
#pragma unroll
        for (int j = 0; j < 8; ++j) dd[j] = dst[eord[g + (j < gcnt ? j : 0)]];
        // stage 8 h1 rows (coalesced float4)
#pragma unroll
        for (int t = 0; t < 4; ++t) {
            int i = t * 256 + lane * 4;
            int j = i >> 7, k = i & 127;
            int ej = eord[g + (j < gcnt ? j : 0)];
            *(float4*)&h1w[j * 128 + k] = *(const float4*)&h1[(size_t)ej * 128 + k];
        }
        float acc[8][8];
#pragma unroll
        for (int j = 0; j < 8; ++j)
#pragma unroll
            for (int c = 0; c < 8; ++c) acc[j][c] = 0.f;
#pragma unroll 4
        for (int kt = 0; kt < 16; ++kt) {
            halfx8 pv = *(const halfx8*)&Pr[(size_t)(kt * 8 + kq) * 64 + og * 8];
            float pf[8];
#pragma unroll
            for (int c = 0; c < 8; ++c) pf[c] = (float)pv[c];
#pragma unroll
            for (int j = 0; j < 8; ++j) {
                float hv = h1w[j * 128 + kt * 8 + kq];
#pragma unroll
                for (int c = 0; c < 8; ++c) acc[j][c] = fmaf(hv, pf[c], acc[j][c]);
            }
        }
        // reduce over the 8 kq groups (xor 8,16,32); kq==0 lanes hold result
#pragma unroll
        for (int j = 0; j < 8; ++j) {
#pragma unroll
            for (int c = 0; c < 8; ++c) {
                float v = acc[j][c];
                v += __shfl_xor(v, 8, 64);
                v += __shfl_xor(v, 16, 64);
                v += __shfl_xor(v, 32, 64);
                acc[j][c] = v;
            }
            if (kq == 0) {
                float4 v0 = {acc[j][0], acc[j][1], acc[j][2], acc[j][3]};
                float4 v1 = {acc[j][4], acc[j][5], acc[j][6], acc[j][7]};
                *(float4*)&redw[j * 64 + og * 8] = v0;
                *(float4*)&redw[j * 64 + og * 8 + 4] = v1;
            }
        }
        for (int j = 0; j < gcnt; ++j)
            atomicAdd(&agg[(size_t)dd[j] * 64 + lane], redw[j * 64 + lane] + qv);
    }
}

// combine (scatter-mean + root + bias + relu) and GRU cell; 32 nodes/block,
// 8 nodes/wave register tiling, root/h/m staged in LDS, weights streamed (L2).
__global__ __launch_bounds__(256) void gru_kernel(float* __restrict__ out,
                                                  const float* __restrict__ agg,
                                                  const float* __restrict__ cnt,
                                                  const float* __restrict__ root,
                                                  const float* __restrict__ cbias,
                                                  const float* __restrict__ wi,
                                                  const float* __restrict__ wh,
                                                  const float* __restrict__ bi,
                                                  const float* __restrict__ bh) {
    __shared__ float root_s[64 * 64];
    __shared__ float h_s[32 * 64];
    __shared__ float m_s[32 * 64];
    int tid = threadIdx.x;
    int lane = tid & 63;
    int wv = __builtin_amdgcn_readfirstlane(tid >> 6);
    int nb = blockIdx.x * 32;
#pragma unroll
    for (int it = 0; it < 4; ++it) {
        int i = it * 1024 + tid * 4;
        *(float4*)&root_s[i] = *(const float4*)&root[i];
    }
#pragma unroll
    for (int it = 0; it < 2; ++it) {
        int i = it * 1024 + tid * 4;
        *(float4*)&h_s[i] = *(const float4*)&out[(size_t)nb * 64 + i];
    }
    __syncthreads();

    int nbase = nb + wv * 8;
    float a[8];
#pragma unroll
    for (int j = 0; j < 8; ++j) {
        int n = nbase + j;
        float c = cnt[n]; c = c > 1.f ? c : 1.f;
        a[j] = agg[(size_t)n * 64 + lane] / c + cbias[lane];
    }
    for (int i = 0; i < 64; ++i) {
        float rv = root_s[i * 64 + lane];
#pragma unroll
        for (int j = 0; j < 8; ++j)
            a[j] = fmaf(h_s[(wv * 8 + j) * 64 + i], rv, a[j]);
    }
#pragma unroll
    for (int j = 0; j < 8; ++j) {
        float m = a[j] > 0.f ? a[j] : 0.f;
        m_s[(wv * 8 + j) * 64 + lane] = m;
    }
    __syncthreads();

    float gir[8], giz[8], gin[8], ghr[8], ghz[8], ghn[8];
    float bi0 = bi[lane], bi1 = bi[64 + lane], bi2 = bi[128 + lane];
    float bh0 = bh[lane], bh1 = bh[64 + lane], bh2 = bh[128 + lane];
#pragma unroll
    for (int j = 0; j < 8; ++j) {
        gir[j] = bi0; giz[j] = bi1; gin[j] = bi2;
        ghr[j] = bh0; ghz[j] = bh1; ghn[j] = bh2;
    }
    for (int i = 0; i < 64; ++i) {
        float w0 = wi[i * 192 + lane];
        float w1 = wi[i * 192 + 64 + lane];
        float w2v = wi[i * 192 + 128 + lane];
        float u0 = wh[i * 192 + lane];
        float u1 = wh[i * 192 + 64 + lane];
        float u2 = wh[i * 192 + 128 + lane];
#pragma unroll
        for (int j = 0; j < 8; ++j) {
            float mi = m_s[(wv * 8 + j) * 64 + i];
            float hi = h_s[(wv * 8 + j) * 64 + i];
            gir[j] = fmaf(mi, w0, gir[j]);
            giz[j] = fmaf(mi, w1, giz[j]);
            gin[j] = fmaf(mi, w2v, gin[j]);
            ghr[j] = fmaf(hi, u0, ghr[j]);
            ghz[j] = fmaf(hi, u1, ghz[j]);
            ghn[j] = fmaf(hi, u2, ghn[j]);
        }
    }
#pragma unroll
    for (int j = 0; j < 8; ++j) {
        int n = nbase + j;
        float rg = 1.f / (1.f + expf(-(gir[j] + ghr[j])));
        float zg = 1.f / (1.f + expf(-(giz[j] + ghz[j])));
        float ng = tanhf(gin[j] + rg * ghn[j]);
        float h = h_s[(wv * 8 + j) * 64 + lane];
        out[(size_t)n * 64 + lane] = (1.f - zg) * ng + zg * h;
    }
}

// Set2Set LSTM cell
__global__ __launch_bounds__(256) void lstm_kernel(const float* __restrict__ q_star,
                                                   float* __restrict__ hl, float* __restrict__ cl,
                                                   const float* __restrict__ wi,
                                                   const float* __restrict__ wh,
                                                   const float* __restrict__ bi,
                                                   const float* __restrict__ bh) {
    int b = blockIdx.x;
    int j = threadIdx.x;
    __shared__ float qs[128], hs[64], g[256];
    if (j < 128) qs[j] = q_star[b * 128 + j];
    if (j < 64) hs[j] = hl[b * 64 + j];
    __syncthreads();
    float acc = bi[j] + bh[j];
#pragma unroll 8
    for (int i = 0; i < 128; ++i) acc = fmaf(qs[i], wi[i * 256 + j], acc);
#pragma unroll 8
    for (int i = 0; i < 64; ++i) acc = fmaf(hs[i], wh[i * 256 + j], acc);
    g[j] = acc;
    __syncthreads();
    if (j < 64) {
        float ig = 1.f / (1.f + expf(-g[j]));
        float fg = 1.f / (1.f + expf(-g[64 + j]));
        float gg = tanhf(g[128 + j]);
        float og = 1.f / (1.f + expf(-g[192 + j]));
        float c = fg * cl[b * 64 + j] + ig * gg;
        cl[b * 64 + j] = c;
        hl[b * 64 + j] = og * tanhf(c);
    }
}

// Set2Set attention
__global__ __launch_bounds__(256) void attn_kernel(const float* __restrict__ out,
                                                   const int* __restrict__ off_b,
                                                   const float* __restrict__ hl,
                                                   float* __restrict__ q_star,
                                                   float* __restrict__ e_ws) {
    int b = blockIdx.x;
    int start = off_b[b], end = off_b[b + 1];
    int t = threadIdx.x;
    __shared__ float q[64];
    __shared__ float red[256];
    __shared__ float racc[256];
    __shared__ float sasum[4];
    if (t < 64) q[t] = hl[b * 64 + t];
    __syncthreads();
    float lmax = -1e30f;
    for (int n = start + t; n < end; n += 256) {
        float acc = 0.f;
#pragma unroll 16
        for (int d2 = 0; d2 < 64; ++d2) acc = fmaf(out[n * 64 + d2], q[d2], acc);
        e_ws[n] = acc;
        lmax = fmaxf(lmax, acc);
    }
    red[t] = lmax;
    __syncthreads();
    for (int s2 = 128; s2 > 0; s2 >>= 1) {
        if (t < s2) red[t] = fmaxf(red[t], red[t + s2]);
        __syncthreads();
    }
    float emax = red[0];
    int w = t >> 6, d = t & 63;
    float rl = 0.f, lasum = 0.f;
    for (int n = start + w; n < end; n += 4) {
        float a = expf(e_ws[n] - emax);
        rl = fmaf(a, out[n * 64 + d], rl);
        if (d == 0) lasum += a;
    }
    racc[t] = rl;
    if (d == 0) sasum[w] = lasum;
    __syncthreads();
    if (t < 64) {
        float r = racc[t] + racc[64 + t] + racc[128 + t] + racc[192 + t];
        float as = sasum[0] + sasum[1] + sasum[2] + sasum[3];
        as = fmaxf(as, 1e-16f);
        q_star[b * 128 + t] = q[t];
        q_star[b * 128 + 64 + t] = r / as;
    }
}

// output head
__global__ __launch_bounds__(64) void head_kernel(const float* __restrict__ q_star,
                                                  const float* __restrict__ w1,
                                                  const float* __restrict__ b1,
                                                  const float* __restrict__ w2,
                                                  const float* __restrict__ b2,
                                                  float* __restrict__ y) {
    int b = blockIdx.x;
    int d = threadIdx.x;
    float qlo = q_star[b * 128 + d];
    float qhi = q_star[b * 128 + 64 + d];
    float acc = b1[d];
#pragma unroll 8
    for (int i = 0; i < 64; ++i) {
        acc = fmaf(__shfl(qlo, i, 64), w1[i * 64 + d], acc);
        acc = fmaf(__shfl(qhi, i, 64), w1[(64 + i) * 64 + d], acc);
    }
    acc = acc > 0.f ? acc : 0.f;
    float p = acc * w2[d];
    for (int off = 32; off > 0; off >>= 1) p += __shfl_down(p, off, 64);
    if (d == 0) y[b] = p + b2[0];
}

extern "C" void kernel_launch(void* const* d_in, const int* in_sizes, int n_in,
                              void* d_out, int out_size, void* d_ws, size_t ws_size,
                              hipStream_t stream) {
    (void)in_sizes; (void)n_in; (void)out_size;
    const float* x        = (const float*)d_in[0];
    const float* ea       = (const float*)d_in[1];
    const int*   eidx     = (const int*)d_in[2];
    const int*   batch    = (const int*)d_in[3];
    const float* lin0_w   = (const float*)d_in[4];
    const float* lin0_b   = (const float*)d_in[5];
    const float* mlp_w1   = (const float*)d_in[6];
    const float* mlp_b1   = (const float*)d_in[7];
    const float* mlp_w2   = (const float*)d_in[8];
    const float* mlp_b2   = (const float*)d_in[9];
    const float* conv_root= (const float*)d_in[10];
    const float* conv_bias= (const float*)d_in[11];
    const float* gru_wi   = (const float*)d_in[12];
    const float* gru_wh   = (const float*)d_in[13];
    const float* gru_bi   = (const float*)d_in[14];
    const float* gru_bh   = (const float*)d_in[15];
    const float* lstm_wi  = (const float*)d_in[16];
    const float* lstm_wh  = (const float*)d_in[17];
    const float* lstm_bi  = (const float*)d_in[18];
    const float* lstm_bh  = (const float*)d_in[19];
    const float* lin1_w   = (const float*)d_in[20];
    const float* lin1_b   = (const float*)d_in[21];
    const float* lin2_w   = (const float*)d_in[22];
    const float* lin2_b   = (const float*)d_in[23];
    float* y = (float*)d_out;

    const int* src = eidx;
    const int* dst = eidx + E_;

    char* w = (char*)d_ws;
    auto carve = [&](size_t bytes) {
        char* p = w;
        w += (bytes + 255) & ~(size_t)255;
        return p;
    };
    float* out_buf = (float*)carve((size_t)N_ * DIM_ * 4);
    float* agg     = (float*)carve((size_t)N_ * DIM_ * 4);
    float* Q       = (float*)carve((size_t)N_ * DIM_ * 4);
    float* e_ws    = (float*)carve((size_t)N_ * 4);
    int*   off_b   = (int*)carve((size_t)(B_ + 1) * 4);
    float* h1      = (float*)carve((size_t)E_ * MLP_H_ * 4);
    unsigned short* Bh = (unsigned short*)carve((size_t)PC_ * 64 * 2);
    unsigned short* Bl = (unsigned short*)carve((size_t)PC_ * 64 * 2);
    int*   src_off = (int*)carve((size_t)(N_ + 1) * 4);
    int*   eord    = (int*)carve((size_t)E_ * 4);
    // contiguous zero zone (single memset)
    char*  zero0   = w;
    float* cnt     = (float*)carve((size_t)N_ * 4);
    int*   cnt_src = (int*)carve((size_t)N_ * 4);
    int*   cur     = (int*)carve((size_t)N_ * 4);
    float* q_star  = (float*)carve((size_t)B_ * 128 * 4);
    float* hl      = (float*)carve((size_t)B_ * 64 * 4);
    float* cl      = (float*)carve((size_t)B_ * 64 * 4);
    size_t zbytes  = (size_t)(w - zero0);

    size_t used = (size_t)(w - (char*)d_ws);
    _Float16* P = (_Float16*)w;
    size_t avail = ws_size > used ? ws_size - used : 0;
    long long nc = (long long)(avail / ((size_t)PC_ * 2));   // fp16 P rows
    if (nc > N_) nc = N_;
    nc &= ~127LL;
    if (nc < 128) nc = 128;
    int NC = (int)nc;

    hipMemsetAsync(zero0, 0, zbytes, stream);

    lin0_kernel<<<(N_ * DIM_ + 255) / 256, 256, 0, stream>>>(x, lin0_w, lin0_b, out_buf);
    mlp1_kernel<<<(E_ * MLP_H_ + 255) / 256, 256, 0, stream>>>(ea, mlp_w1, mlp_b1, h1);
    cnt_kernel<<<(E_ + 255) / 256, 256, 0, stream>>>(dst, cnt);
    batch_off_kernel<<<1, 256, 0, stream>>>(batch, off_b);
    hist_src<<<(E_ + 255) / 256, 256, 0, stream>>>(src, cnt_src);
    scan_src<<<1, 256, 0, stream>>>(cnt_src, src_off);
    scatter_src<<<(E_ + 255) / 256, 256, 0, stream>>>(src, cur, src_off, eord);
    prep_b<<<(PC_ * 64 + 255) / 256, 256, 0, stream>>>(mlp_w2, Bh, Bl);

    for (int step = 0; step < 3; ++step) {
        q_kernel<<<(N_ + 3) / 4, 256, 0, stream>>>(out_buf, mlp_b2, Q);
        hipMemsetAsync(agg, 0, (size_t)N_ * DIM_ * 4, stream);
        for (int n0 = 0; n0 < N_; n0 += NC) {
            int n1 = n0 + NC < N_ ? n0 + NC : N_;
            dim3 g(PC_ / 128, (n1 - n0 + 127) / 128);
            p_gemm_mfma<<<g, 256, 0, stream>>>(out_buf, Bh, Bl, P, n0, n1);
            int nn = n1 - n0;
            edge_msg<<<(nn + 3) / 4, 256, 0, stream>>>(P, h1, Q, eord, dst,
                                                       src_off, agg, n0, n1);
        }
        gru_kernel<<<N_ / 32, 256, 0, stream>>>(out_buf, agg, cnt, conv_root, conv_bias,
                                                gru_wi, gru_wh, gru_bi, gru_bh);
    }

    for (int s = 0; s < 3; ++s) {
        lstm_kernel<<<B_, 256, 0, stream>>>(q_star, hl, cl, lstm_wi, lstm_wh, lstm_bi, lstm_bh);
        attn_kernel<<<B_, 256, 0, stream>>>(out_buf, off_b, hl, q_star, e_ws);
    }
    head_kernel<<<B_, 64, 0, stream>>>(q_star, lin1_w, lin1_b, lin2_w, lin2_b, y);
}

// Round 10
// 1183.504 us; speedup vs baseline: 2.1090x; 1.1135x over previous
//
#include <hip/hip_runtime.h>
#include <math.h>

// Problem dims (fixed)
#define N_ 20000
#define E_ 100000
#define B_ 128
#define F_IN_ 14
#define DIM_ 64
#define E_FEAT_ 4
#define MLP_H_ 128
#define EWC_ 4096    // DIM*DIM
#define PC_ 8192     // MLP_H * DIM (P columns)

typedef __attribute__((ext_vector_type(8))) short bf16x8;
typedef __attribute__((ext_vector_type(4))) float f32x4;
typedef __attribute__((ext_vector_type(8))) _Float16 halfx8;

__device__ __forceinline__ unsigned short f2bf_rn(float f) {
    unsigned int u = __float_as_uint(f);
    unsigned int r = (u + 0x7fffu + ((u >> 16) & 1u)) >> 16;
    return (unsigned short)r;
}
__device__ __forceinline__ float bf2f(unsigned short h) {
    return __uint_as_float(((unsigned int)h) << 16);
}

// ---------------------------------------------------------------------------
// lin0: out[n,d] = relu(x[n,:] @ lin0_w + b)
__global__ void lin0_kernel(const float* __restrict__ x, const float* __restrict__ w,
                            const float* __restrict__ b, float* __restrict__ out) {
    int idx = blockIdx.x * blockDim.x + threadIdx.x;
    if (idx >= N_ * DIM_) return;
    int n = idx >> 6, d = idx & 63;
    float acc = b[d];
#pragma unroll
    for (int f = 0; f < F_IN_; ++f) acc = fmaf(x[n * F_IN_ + f], w[f * DIM_ + d], acc);
    out[idx] = acc > 0.f ? acc : 0.f;
}

// edge MLP layer 1, ROW-major fp16: h1[e*128 + k] = relu(ea[e,:] @ w1 + b1)[k]
__global__ void mlp1_kernel(const float* __restrict__ ea, const float* __restrict__ w1,
                            const float* __restrict__ b1, _Float16* __restrict__ h1) {
    int idx = blockIdx.x * blockDim.x + threadIdx.x;
    if (idx >= E_ * MLP_H_) return;
    int e = idx >> 7, k = idx & 127;
    float acc = b1[k];
#pragma unroll
    for (int f = 0; f < E_FEAT_; ++f) acc = fmaf(ea[e * E_FEAT_ + f], w1[f * MLP_H_ + k], acc);
    h1[idx] = (_Float16)(acc > 0.f ? acc : 0.f);
}

// incoming-edge counts (float, for mean)
__global__ void cnt_kernel(const int* __restrict__ dst, float* __restrict__ cnt) {
    int e = blockIdx.x * blockDim.x + threadIdx.x;
    if (e >= E_) return;
    atomicAdd(&cnt[dst[e]], 1.0f);
}

// batch is SORTED: off_b[b] = lower_bound(batch, b). Replaces atomic histogram.
__global__ void batch_off_kernel(const int* __restrict__ batch, int* __restrict__ off_b) {
    int b = threadIdx.x;
    if (b > B_) return;
    int lo = 0, hi = N_;
    while (lo < hi) {
        int mid = (lo + hi) >> 1;
        if (batch[mid] < b) lo = mid + 1; else hi = mid;
    }
    off_b[b] = lo;
}

// src histogram for counting sort
__global__ void hist_src(const int* __restrict__ src, int* __restrict__ cnt_src) {
    int e = blockIdx.x * blockDim.x + threadIdx.x;
    if (e >= E_) return;
    atomicAdd(&cnt_src[src[e]], 1);
}

// exclusive scan over N_ bins -> src_off[0..N_]
__global__ void scan_src(const int* __restrict__ cnt_src, int* __restrict__ src_off) {
    __shared__ int part[256];
    __shared__ int off[257];
    int t = threadIdx.x;
    const int per = (N_ + 255) / 256;
    int base = t * per;
    int s = 0;
    for (int i = 0; i < per; ++i) { int b = base + i; if (b < N_) s += cnt_src[b]; }
    part[t] = s;
    __syncthreads();
    if (t == 0) {
        int a = 0;
        for (int i = 0; i < 256; ++i) { off[i] = a; a += part[i]; }
        off[256] = a;
    }
    __syncthreads();
    int run = off[t];
    for (int i = 0; i < per; ++i) {
        int b = base + i;
        if (b < N_) { src_off[b] = run; run += cnt_src[b]; }
    }
    if (t == 0) src_off[N_] = off[256];
}

// scatter edges into src-sorted order
__global__ void scatter_src(const int* __restrict__ src, int* __restrict__ cur,
                            const int* __restrict__ src_off, int* __restrict__ eord) {
    int e = blockIdx.x * blockDim.x + threadIdx.x;
    if (e >= E_) return;
    int s = src[e];
    int p = src_off[s] + atomicAdd(&cur[s], 1);
    eord[p] = e;
}

// B prep (once), TRANSPOSED column order c = o*128 + k:
// Bh/Bl[c*64 + i] = bf16 hi/lo of w2[k*4096 + i*64 + o]
// => p_gemm produces P'[node, o*128 + k] (k-contiguous rows for edge_msg MFMA).
__global__ void prep_b(const float* __restrict__ w2,
                       unsigned short* __restrict__ Bh,
                       unsigned short* __restrict__ Bl) {
    int idx = blockIdx.x * blockDim.x + threadIdx.x;
    if (idx >= PC_ * 64) return;
    int c = idx >> 6, i = idx & 63;
    int o = c >> 7, k = c & 127;
    float v = w2[(size_t)k * EWC_ + i * 64 + o];
    unsigned short h = f2bf_rn(v);
    Bh[idx] = h;
    Bl[idx] = f2bf_rn(v - bf2f(h));
}

// Q[n,o] = sum_i out[n,i] * b2[i*64+o] — wave/node, b2 staged in LDS
__global__ __launch_bounds__(256) void q_kernel(const float* __restrict__ out,
                                                const float* __restrict__ b2,
                                                float* __restrict__ Q) {
    __shared__ float b2s[64 * 64];
    int tid = threadIdx.x;
#pragma unroll
    for (int it = 0; it < 4; ++it) {
        int i = it * 1024 + tid * 4;
        *(float4*)&b2s[i] = *(const float4*)&b2[i];
    }
    __syncthreads();
    int wv = __builtin_amdgcn_readfirstlane(tid >> 6);
    int n = blockIdx.x * 4 + wv;
    if (n >= N_) return;
    int o = tid & 63;
    float ov = out[(size_t)n * 64 + o];
    float acc = 0.f;
#pragma unroll 8
    for (int i = 0; i < 64; ++i) acc = fmaf(__shfl(ov, i, 64), b2s[i * 64 + o], acc);
    Q[(size_t)n * 64 + o] = acc;
}

// ---------------------------------------------------------------------------
// P GEMM via split-bf16 MFMA, fp16 OUTPUT (unchanged from r9; column semantics
// are now transposed via prep_b, code identical).
#define STSTR_ 136
__global__ __launch_bounds__(256) void p_gemm_mfma(const float* __restrict__ out,
                                                   const unsigned short* __restrict__ Bh,
                                                   const unsigned short* __restrict__ Bl,
                                                   _Float16* __restrict__ P,
                                                   int n0, int n1) {
    __shared__ _Float16 st[128 * STSTR_];   // 34.8 KB
    int tid = threadIdx.x;
    int lane = tid & 63;
    int wid = tid >> 6;
    int wm = (wid & 1) * 64;
    int wn = (wid >> 1) * 64;
    int mloc0 = blockIdx.y * 128;
    int nbase = blockIdx.x * 128;
    int lrow = lane & 15, quad = lane >> 4;

    bf16x8 bhf[4][2], blf[4][2];
#pragma unroll
    for (int nf = 0; nf < 4; ++nf)
#pragma unroll
        for (int ks = 0; ks < 2; ++ks) {
            size_t g = (size_t)(nbase + wn + nf * 16 + lrow) * 64 + ks * 32 + quad * 8;
            bhf[nf][ks] = *(const bf16x8*)&Bh[g];
            blf[nf][ks] = *(const bf16x8*)&Bl[g];
        }

    f32x4 acc[4][4];
#pragma unroll
    for (int a = 0; a < 4; ++a)
#pragma unroll
        for (int b = 0; b < 4; ++b) acc[a][b] = (f32x4){0.f, 0.f, 0.f, 0.f};

#pragma unroll
    for (int mf = 0; mf < 4; ++mf) {
        int gm = n0 + mloc0 + wm + mf * 16 + lrow;
        bf16x8 ahf[2], alf[2];
#pragma unroll
        for (int ks = 0; ks < 2; ++ks) {
            float v[8];
            if (gm < n1) {
                float4 v0 = *(const float4*)&out[(size_t)gm * 64 + ks * 32 + quad * 8];
                float4 v1 = *(const float4*)&out[(size_t)gm * 64 + ks * 32 + quad * 8 + 4];
                v[0] = v0.x; v[1] = v0.y; v[2] = v0.z; v[3] = v0.w;
                v[4] = v1.x; v[5] = v1.y; v[6] = v1.z; v[7] = v1.w;
            } else {
#pragma unroll
                for (int i = 0; i < 8; ++i) v[i] = 0.f;
            }
#pragma unroll
            for (int i = 0; i < 8; ++i) {
                unsigned short hh = f2bf_rn(v[i]);
                ahf[ks][i] = (short)hh;
                alf[ks][i] = (short)f2bf_rn(v[i] - bf2f(hh));
            }
        }
#pragma unroll
        for (int nf = 0; nf < 4; ++nf) {
#pragma unroll
            for (int ks = 0; ks < 2; ++ks) {
                acc[mf][nf] = __builtin_amdgcn_mfma_f32_16x16x32_bf16(
                    ahf[ks], bhf[nf][ks], acc[mf][nf], 0, 0, 0);
                acc[mf][nf] = __builtin_amdgcn_mfma_f32_16x16x32_bf16(
                    alf[ks], bhf[nf][ks], acc[mf][nf], 0, 0, 0);
                acc[mf][nf] = __builtin_amdgcn_mfma_f32_16x16x32_bf16(
                    ahf[ks], blf[nf][ks], acc[mf][nf], 0, 0, 0);
            }
        }
    }

#pragma unroll
    for (int mf = 0; mf < 4; ++mf)
#pragma unroll
        for (int nf = 0; nf < 4; ++nf)
#pragma unroll
            for (int r = 0; r < 4; ++r) {
                int row = wm + mf * 16 + quad * 4 + r;
                int col = wn + nf * 16 + lrow;
                st[row * STSTR_ + col] = (_Float16)acc[mf][nf][r];
            }
    __syncthreads();
#pragma unroll
    for (int it = 0; it < 8; ++it) {
        int chunk = it * 256 + tid;
        int row = chunk >> 4;
        int cb = (chunk & 15) * 8;
        if (n0 + mloc0 + row < n1) {
            int4 v = *(const int4*)&st[row * STSTR_ + cb];
            *(int4*)&P[(size_t)(mloc0 + row) * PC_ + nbase + cb] = v;
        }
    }
}

// ---------------------------------------------------------------------------
// edge_msg via fp16 MFMA: per src node, msg-block (16 edges x 64 o) =
// H(16x128 fp16) @ P_n^T(128x64 fp16 as B[o][k]).  Wave per node; B-frags
// (full 16KB P' row) loaded once per node; groups of 16 edges -> 16 MFMAs.
// A[m=lane&15 -> edge][k=quad*8+i]; B[n=lane&15 -> o][k]; D col=o, row=edge
// (m89-verified layout, dtype-independent). No LDS, no shfl-reduce.
__global__ __launch_bounds__(256) void edge_msg(const _Float16* __restrict__ P,
                                                const _Float16* __restrict__ h1,
                                                const float* __restrict__ Q,
                                                const int* __restrict__ eord,
                                                const int* __restrict__ dst,
                                                const int* __restrict__ src_off,
                                                float* __restrict__ agg,
                                                int n0, int n1) {
    int wv = __builtin_amdgcn_readfirstlane((int)(threadIdx.x >> 6));
    int r = blockIdx.x * 4 + wv;
    int n = n0 + r;
    if (n >= n1) return;
    int lane = threadIdx.x & 63;
    int lrow = lane & 15, quad = lane >> 4;
    int beg = src_off[n], end2 = src_off[n + 1];
    if (beg == end2) return;
    const _Float16* Pr = P + (size_t)r * PC_;

    // B fragments: o = nf*16 + lrow, k = ks*32 + quad*8 (held across all groups)
    halfx8 bf[4][4];
#pragma unroll
    for (int nf = 0; nf < 4; ++nf)
#pragma unroll
        for (int ks = 0; ks < 4; ++ks)
            bf[nf][ks] = *(const halfx8*)&Pr[(nf * 16 + lrow) * 128 + ks * 32 + quad * 8];
    float qv[4];
#pragma unroll
    for (int nf = 0; nf < 4; ++nf) qv[nf] = Q[(size_t)n * 64 + nf * 16 + lrow];

    for (int g = beg; g < end2; g += 16) {
        int gcnt = end2 - g; if (gcnt > 16) gcnt = 16;
        int ei = lrow < gcnt ? lrow : gcnt - 1;
        int ej = eord[g + ei];
        int dv = dst[ej];
        // A fragments: edge = lrow, k = ks*32 + quad*8
        halfx8 af[4];
#pragma unroll
        for (int ks = 0; ks < 4; ++ks)
            af[ks] = *(const halfx8*)&h1[(size_t)ej * 128 + ks * 32 + quad * 8];
        f32x4 acc[4];
#pragma unroll
        for (int nf = 0; nf < 4; ++nf) acc[nf] = (f32x4){0.f, 0.f, 0.f, 0.f};
#pragma unroll
        for (int nf = 0; nf < 4; ++nf)
#pragma unroll
            for (int ks = 0; ks < 4; ++ks)
                acc[nf] = __builtin_amdgcn_mfma_f32_16x16x32_f16(
                    af[ks], bf[nf][ks], acc[nf], 0, 0, 0);
        // epilogue: D row (quad*4+rr) = edge j, col (nf*16+lrow) = o
#pragma unroll
        for (int rr = 0; rr < 4; ++rr) {
            int j = quad * 4 + rr;
            int d = __shfl(dv, j, 64);
            if (j < gcnt) {
#pragma unroll
                for (int nf = 0; nf < 4; ++nf)
                    atomicAdd(&agg[(size_t)d * 64 + nf * 16 + lrow],
                              acc[nf][rr] + qv[nf]);
            }
        }
    }
}

// combine (scatter-mean + root + bias + relu) and GRU cell; 32 nodes/block,
// 8 nodes/wave register tiling, root/h/m staged in LDS, weights streamed (L2).
__global__ __launch_bounds__(256) void gru_kernel(float* __restrict__ out,
                                                  const float* __restrict__ agg,
                                                  const float* __restrict__ cnt,
                                                  const float* __restrict__ root,
                                                  const float* __restrict__ cbias,
                                                  const float* __restrict__ wi,
                                                  const float* __restrict__ wh,
                                                  const float* __restrict__ bi,
                                                  const float* __restrict__ bh) {
    __shared__ float root_s[64 * 64];
    __shared__ float h_s[32 * 64];
    __shared__ float m_s[32 * 64];
    int tid = threadIdx.x;
    int lane = tid & 63;
    int wv = __builtin_amdgcn_readfirstlane(tid >> 6);
    int nb = blockIdx.x * 32;
#pragma unroll
    for (int it = 0; it < 4; ++it) {
        int i = it * 1024 + tid * 4;
        *(float4*)&root_s[i] = *(const float4*)&root[i];
    }
#pragma unroll
    for (int it = 0; it < 2; ++it) {
        int i = it * 1024 + tid * 4;
        *(float4*)&h_s[i] = *(const float4*)&out[(size_t)nb * 64 + i];
    }
    __syncthreads();

    int nbase = nb + wv * 8;
    float a[8];
#pragma unroll
    for (int j = 0; j < 8; ++j) {
        int n = nbase + j;
        float c = cnt[n]; c = c > 1.f ? c : 1.f;
        a[j] = agg[(size_t)n * 64 + lane] / c + cbias[lane];
    }
    for (int i = 0; i < 64; ++i) {
        float rv = root_s[i * 64 + lane];
#pragma unroll
        for (int j = 0; j < 8; ++j)
            a[j] = fmaf(h_s[(wv * 8 + j) * 64 + i], rv, a[j]);
    }
#pragma unroll
    for (int j = 0; j < 8; ++j) {
        float m = a[j] > 0.f ? a[j] : 0.f;
        m_s[(wv * 8 + j) * 64 + lane] = m;
    }
    __syncthreads();

    float gir[8], giz[8], gin[8], ghr[8], ghz[8], ghn[8];
    float bi0 = bi[lane], bi1 = bi[64 + lane], bi2 = bi[128 + lane];
    float bh0 = bh[lane], bh1 = bh[64 + lane], bh2 = bh[128 + lane];
#pragma unroll
    for (int j = 0; j < 8; ++j) {
        gir[j] = bi0; giz[j] = bi1; gin[j] = bi2;
        ghr[j] = bh0; ghz[j] = bh1; ghn[j] = bh2;
    }
    for (int i = 0; i < 64; ++i) {
        float w0 = wi[i * 192 + lane];
        float w1 = wi[i * 192 + 64 + lane];
        float w2v = wi[i * 192 + 128 + lane];
        float u0 = wh[i * 192 + lane];
        float u1 = wh[i * 192 + 64 + lane];
        float u2 = wh[i * 192 + 128 + lane];
#pragma unroll
        for (int j = 0; j < 8; ++j) {
            float mi = m_s[(wv * 8 + j) * 64 + i];
            float hi = h_s[(wv * 8 + j) * 64 + i];
            gir[j] = fmaf(mi, w0, gir[j]);
            giz[j] = fmaf(mi, w1, giz[j]);
            gin[j] = fmaf(mi, w2v, gin[j]);
            ghr[j] = fmaf(hi, u0, ghr[j]);
            ghz[j] = fmaf(hi, u1, ghz[j]);
            ghn[j] = fmaf(hi, u2, ghn[j]);
        }
    }
#pragma unroll
    for (int j = 0; j < 8; ++j) {
        int n = nbase + j;
        float rg = 1.f / (1.f + expf(-(gir[j] + ghr[j])));
        float zg = 1.f / (1.f + expf(-(giz[j] + ghz[j])));
        float ng = tanhf(gin[j] + rg * ghn[j]);
        float h = h_s[(wv * 8 + j) * 64 + lane];
        out[(size_t)n * 64 + lane] = (1.f - zg) * ng + zg * h;
    }
}

// Set2Set LSTM cell
__global__ __launch_bounds__(256) void lstm_kernel(const float* __restrict__ q_star,
                                                   float* __restrict__ hl, float* __restrict__ cl,
                                                   const float* __restrict__ wi,
                                                   const float* __restrict__ wh,
                                                   const float* __restrict__ bi,
                                                   const float* __restrict__ bh) {
    int b = blockIdx.x;
    int j = threadIdx.x;
    __shared__ float qs[128], hs[64], g[256];
    if (j < 128) qs[j] = q_star[b * 128 + j];
    if (j < 64) hs[j] = hl[b * 64 + j];
    __syncthreads();
    float acc = bi[j] + bh[j];
#pragma unroll 8
    for (int i = 0; i < 128; ++i) acc = fmaf(qs[i], wi[i * 256 + j], acc);
#pragma unroll 8
    for (int i = 0; i < 64; ++i) acc = fmaf(hs[i], wh[i * 256 + j], acc);
    g[j] = acc;
    __syncthreads();
    if (j < 64) {
        float ig = 1.f / (1.f + expf(-g[j]));
        float fg = 1.f / (1.f + expf(-g[64 + j]));
        float gg = tanhf(g[128 + j]);
        float og = 1.f / (1.f + expf(-g[192 + j]));
        float c = fg * cl[b * 64 + j] + ig * gg;
        cl[b * 64 + j] = c;
        hl[b * 64 + j] = og * tanhf(c);
    }
}

// Set2Set attention
__global__ __launch_bounds__(256) void attn_kernel(const float* __restrict__ out,
                                                   const int* __restrict__ off_b,
                                                   const float* __restrict__ hl,
                                                   float* __restrict__ q_star,
                                                   float* __restrict__ e_ws) {
    int b = blockIdx.x;
    int start = off_b[b], end = off_b[b + 1];
    int t = threadIdx.x;
    __shared__ float q[64];
    __shared__ float red[256];
    __shared__ float racc[256];
    __shared__ float sasum[4];
    if (t < 64) q[t] = hl[b * 64 + t];
    __syncthreads();
    float lmax = -1e30f;
    for (int n = start + t; n < end; n += 256) {
        float acc = 0.f;
#pragma unroll 16
        for (int d2 = 0; d2 < 64; ++d2) acc = fmaf(out[n * 64 + d2], q[d2], acc);
        e_ws[n] = acc;
        lmax = fmaxf(lmax, acc);
    }
    red[t] = lmax;
    __syncthreads();
    for (int s2 = 128; s2 > 0; s2 >>= 1) {
        if (t < s2) red[t] = fmaxf(red[t], red[t + s2]);
        __syncthreads();
    }
    float emax = red[0];
    int w = t >> 6, d = t & 63;
    float rl = 0.f, lasum = 0.f;
    for (int n = start + w; n < end; n += 4) {
        float a = expf(e_ws[n] - emax);
        rl = fmaf(a, out[n * 64 + d], rl);
        if (d == 0) lasum += a;
    }
    racc[t] = rl;
    if (d == 0) sasum[w] = lasum;
    __syncthreads();
    if (t < 64) {
        float r = racc[t] + racc[64 + t] + racc[128 + t] + racc[192 + t];
        float as = sasum[0] + sasum[1] + sasum[2] + sasum[3];
        as = fmaxf(as, 1e-16f);
        q_star[b * 128 + t] = q[t];
        q_star[b * 128 + 64 + t] = r / as;
    }
}

// output head
__global__ __launch_bounds__(64) void head_kernel(const float* __restrict__ q_star,
                                                  const float* __restrict__ w1,
                                                  const float* __restrict__ b1,
                                                  const float* __restrict__ w2,
                                                  const float* __restrict__ b2,
                                                  float* __restrict__ y) {
    int b = blockIdx.x;
    int d = threadIdx.x;
    float qlo = q_star[b * 128 + d];
    float qhi = q_star[b * 128 + 64 + d];
    float acc = b1[d];
#pragma unroll 8
    for (int i = 0; i < 64; ++i) {
        acc = fmaf(__shfl(qlo, i, 64), w1[i * 64 + d], acc);
        acc = fmaf(__shfl(qhi, i, 64), w1[(64 + i) * 64 + d], acc);
    }
    acc = acc > 0.f ? acc : 0.f;
    float p = acc * w2[d];
    for (int off = 32; off > 0; off >>= 1) p += __shfl_down(p, off, 64);
    if (d == 0) y[b] = p + b2[0];
}

extern "C" void kernel_launch(void* const* d_in, const int* in_sizes, int n_in,
                              void* d_out, int out_size, void* d_ws, size_t ws_size,
                              hipStream_t stream) {
    (void)in_sizes; (void)n_in; (void)out_size;
    const float* x        = (const float*)d_in[0];
    const float* ea       = (const float*)d_in[1];
    const int*   eidx     = (const int*)d_in[2];
    const int*   batch    = (const int*)d_in[3];
    const float* lin0_w   = (const float*)d_in[4];
    const float* lin0_b   = (const float*)d_in[5];
    const float* mlp_w1   = (const float*)d_in[6];
    const float* mlp_b1   = (const float*)d_in[7];
    const float* mlp_w2   = (const float*)d_in[8];
    const float* mlp_b2   = (const float*)d_in[9];
    const float* conv_root= (const float*)d_in[10];
    const float* conv_bias= (const float*)d_in[11];
    const float* gru_wi   = (const float*)d_in[12];
    const float* gru_wh   = (const float*)d_in[13];
    const float* gru_bi   = (const float*)d_in[14];
    const float* gru_bh   = (const float*)d_in[15];
    const float* lstm_wi  = (const float*)d_in[16];
    const float* lstm_wh  = (const float*)d_in[17];
    const float* lstm_bi  = (const float*)d_in[18];
    const float* lstm_bh  = (const float*)d_in[19];
    const float* lin1_w   = (const float*)d_in[20];
    const float* lin1_b   = (const float*)d_in[21];
    const float* lin2_w   = (const float*)d_in[22];
    const float* lin2_b   = (const float*)d_in[23];
    float* y = (float*)d_out;

    const int* src = eidx;
    const int* dst = eidx + E_;

    char* w = (char*)d_ws;
    auto carve = [&](size_t bytes) {
        char* p = w;
        w += (bytes + 255) & ~(size_t)255;
        return p;
    };
    float* out_buf = (float*)carve((size_t)N_ * DIM_ * 4);
    float* agg     = (float*)carve((size_t)N_ * DIM_ * 4);
    float* Q       = (float*)carve((size_t)N_ * DIM_ * 4);
    float* e_ws    = (float*)carve((size_t)N_ * 4);
    int*   off_b   = (int*)carve((size_t)(B_ + 1) * 4);
    _Float16* h1   = (_Float16*)carve((size_t)E_ * MLP_H_ * 2);
    unsigned short* Bh = (unsigned short*)carve((size_t)PC_ * 64 * 2);
    unsigned short* Bl = (unsigned short*)carve((size_t)PC_ * 64 * 2);
    int*   src_off = (int*)carve((size_t)(N_ + 1) * 4);
    int*   eord    = (int*)carve((size_t)E_ * 4);
    // contiguous zero zone (single memset)
    char*  zero0   = w;
    float* cnt     = (float*)carve((size_t)N_ * 4);
    int*   cnt_src = (int*)carve((size_t)N_ * 4);
    int*   cur     = (int*)carve((size_t)N_ * 4);
    float* q_star  = (float*)carve((size_t)B_ * 128 * 4);
    float* hl      = (float*)carve((size_t)B_ * 64 * 4);
    float* cl      = (float*)carve((size_t)B_ * 64 * 4);
    size_t zbytes  = (size_t)(w - zero0);

    size_t used = (size_t)(w - (char*)d_ws);
    _Float16* P = (_Float16*)w;
    size_t avail = ws_size > used ? ws_size - used : 0;
    long long nc = (long long)(avail / ((size_t)PC_ * 2));   // fp16 P rows
    if (nc > N_) nc = N_;
    nc &= ~127LL;
    if (nc < 128) nc = 128;
    int NC = (int)nc;

    hipMemsetAsync(zero0, 0, zbytes, stream);

    lin0_kernel<<<(N_ * DIM_ + 255) / 256, 256, 0, stream>>>(x, lin0_w, lin0_b, out_buf);
    mlp1_kernel<<<(E_ * MLP_H_ + 255) / 256, 256, 0, stream>>>(ea, mlp_w1, mlp_b1, h1);
    cnt_kernel<<<(E_ + 255) / 256, 256, 0, stream>>>(dst, cnt);
    batch_off_kernel<<<1, 256, 0, stream>>>(batch, off_b);
    hist_src<<<(E_ + 255) / 256, 256, 0, stream>>>(src, cnt_src);
    scan_src<<<1, 256, 0, stream>>>(cnt_src, src_off);
    scatter_src<<<(E_ + 255) / 256, 256, 0, stream>>>(src, cur, src_off, eord);
    prep_b<<<(PC_ * 64 + 255) / 256, 256, 0, stream>>>(mlp_w2, Bh, Bl);

    for (int step = 0; step < 3; ++step) {
        q_kernel<<<(N_ + 3) / 4, 256, 0, stream>>>(out_buf, mlp_b2, Q);
        hipMemsetAsync(agg, 0, (size_t)N_ * DIM_ * 4, stream);
        for (int n0 = 0; n0 < N_; n0 += NC) {
            int n1 = n0 + NC < N_ ? n0 + NC : N_;
            dim3 g(PC_ / 128, (n1 - n0 + 127) / 128);
            p_gemm_mfma<<<g, 256, 0, stream>>>(out_buf, Bh, Bl, P, n0, n1);
            int nn = n1 - n0;
            edge_msg<<<(nn + 3) / 4, 256, 0, stream>>>(P, h1, Q, eord, dst,
                                                       src_off, agg, n0, n1);
        }
        gru_kernel<<<N_ / 32, 256, 0, stream>>>(out_buf, agg, cnt, conv_root, conv_bias,
                                                gru_wi, gru_wh, gru_bi, gru_bh);
    }

    for (int s = 0; s < 3; ++s) {
        lstm_kernel<<<B_, 256, 0, stream>>>(q_star, hl, cl, lstm_wi, lstm_wh, lstm_bi, lstm_bh);
        attn_kernel<<<B_, 256, 0, stream>>>(out_buf, off_b, hl, q_star, e_ws);
    }
    head_kernel<<<B_, 64, 0, stream>>>(q_star, lin1_w, lin1_b, lin2_w, lin2_b, y);
}

// Round 11
// 1002.078 us; speedup vs baseline: 2.4908x; 1.1810x over previous
//
#include <hip/hip_runtime.h>
#include <math.h>

// Problem dims (fixed)
#define N_ 20000
#define E_ 100000
#define B_ 128
#define F_IN_ 14
#define DIM_ 64
#define E_FEAT_ 4
#define MLP_H_ 128
#define EWC_ 4096    // DIM*DIM
#define PC_ 8192     // MLP_H * DIM (P columns)

typedef __attribute__((ext_vector_type(4))) float f32x4;
typedef __attribute__((ext_vector_type(8))) _Float16 halfx8;

// ---------------------------------------------------------------------------
// lin0: out[n,d] = relu(x[n,:] @ lin0_w + b)
__global__ void lin0_kernel(const float* __restrict__ x, const float* __restrict__ w,
                            const float* __restrict__ b, float* __restrict__ out) {
    int idx = blockIdx.x * blockDim.x + threadIdx.x;
    if (idx >= N_ * DIM_) return;
    int n = idx >> 6, d = idx & 63;
    float acc = b[d];
#pragma unroll
    for (int f = 0; f < F_IN_; ++f) acc = fmaf(x[n * F_IN_ + f], w[f * DIM_ + d], acc);
    out[idx] = acc > 0.f ? acc : 0.f;
}

// edge MLP layer 1, ROW-major fp16: h1[e*128 + k] = relu(ea[e,:] @ w1 + b1)[k]
__global__ void mlp1_kernel(const float* __restrict__ ea, const float* __restrict__ w1,
                            const float* __restrict__ b1, _Float16* __restrict__ h1) {
    int idx = blockIdx.x * blockDim.x + threadIdx.x;
    if (idx >= E_ * MLP_H_) return;
    int e = idx >> 7, k = idx & 127;
    float acc = b1[k];
#pragma unroll
    for (int f = 0; f < E_FEAT_; ++f) acc = fmaf(ea[e * E_FEAT_ + f], w1[f * MLP_H_ + k], acc);
    h1[idx] = (_Float16)(acc > 0.f ? acc : 0.f);
}

// incoming-edge counts (float, for mean)
__global__ void cnt_kernel(const int* __restrict__ dst, float* __restrict__ cnt) {
    int e = blockIdx.x * blockDim.x + threadIdx.x;
    if (e >= E_) return;
    atomicAdd(&cnt[dst[e]], 1.0f);
}

// batch is SORTED: off_b[b] = lower_bound(batch, b).
__global__ void batch_off_kernel(const int* __restrict__ batch, int* __restrict__ off_b) {
    int b = threadIdx.x;
    if (b > B_) return;
    int lo = 0, hi = N_;
    while (lo < hi) {
        int mid = (lo + hi) >> 1;
        if (batch[mid] < b) lo = mid + 1; else hi = mid;
    }
    off_b[b] = lo;
}

// src histogram for counting sort
__global__ void hist_src(const int* __restrict__ src, int* __restrict__ cnt_src) {
    int e = blockIdx.x * blockDim.x + threadIdx.x;
    if (e >= E_) return;
    atomicAdd(&cnt_src[src[e]], 1);
}

// exclusive scan over N_ bins -> src_off[0..N_]
__global__ void scan_src(const int* __restrict__ cnt_src, int* __restrict__ src_off) {
    __shared__ int part[256];
    __shared__ int off[257];
    int t = threadIdx.x;
    const int per = (N_ + 255) / 256;
    int base = t * per;
    int s = 0;
    for (int i = 0; i < per; ++i) { int b = base + i; if (b < N_) s += cnt_src[b]; }
    part[t] = s;
    __syncthreads();
    if (t == 0) {
        int a = 0;
        for (int i = 0; i < 256; ++i) { off[i] = a; a += part[i]; }
        off[256] = a;
    }
    __syncthreads();
    int run = off[t];
    for (int i = 0; i < per; ++i) {
        int b = base + i;
        if (b < N_) { src_off[b] = run; run += cnt_src[b]; }
    }
    if (t == 0) src_off[N_] = off[256];
}

// scatter edges into src-sorted order
__global__ void scatter_src(const int* __restrict__ src, int* __restrict__ cur,
                            const int* __restrict__ src_off, int* __restrict__ eord) {
    int e = blockIdx.x * blockDim.x + threadIdx.x;
    if (e >= E_) return;
    int s = src[e];
    int p = src_off[s] + atomicAdd(&cur[s], 1);
    eord[p] = e;
}

// B prep (once), fp16, TRANSPOSED column order c = o*128 + k:
// Bf[c*64 + i] = (fp16) w2[k*4096 + i*64 + o]
__global__ void prep_b(const float* __restrict__ w2, _Float16* __restrict__ Bf) {
    int idx = blockIdx.x * blockDim.x + threadIdx.x;
    if (idx >= PC_ * 64) return;
    int c = idx >> 6, i = idx & 63;
    int o = c >> 7, k = c & 127;
    Bf[idx] = (_Float16)w2[(size_t)k * EWC_ + i * 64 + o];
}

// Q[n,o] = sum_i out[n,i] * b2[i*64+o] — wave/node, b2 staged in LDS
__global__ __launch_bounds__(256) void q_kernel(const float* __restrict__ out,
                                                const float* __restrict__ b2,
                                                float* __restrict__ Q) {
    __shared__ float b2s[64 * 64];
    int tid = threadIdx.x;
#pragma unroll
    for (int it = 0; it < 4; ++it) {
        int i = it * 1024 + tid * 4;
        *(float4*)&b2s[i] = *(const float4*)&b2[i];
    }
    __syncthreads();
    int wv = __builtin_amdgcn_readfirstlane(tid >> 6);
    int n = blockIdx.x * 4 + wv;
    if (n >= N_) return;
    int o = tid & 63;
    float ov = out[(size_t)n * 64 + o];
    float acc = 0.f;
#pragma unroll 8
    for (int i = 0; i < 64; ++i) acc = fmaf(__shfl(ov, i, 64), b2s[i * 64 + o], acc);
    Q[(size_t)n * 64 + o] = acc;
}

// ---------------------------------------------------------------------------
// P GEMM via single fp16 MFMA: P'[r, c] = out[n0+r,:] (64) @ Bf[64 x 8192].
// fp16 inputs (out cvt'd in-register), fp32 accumulate, fp16 store.
// Block = 128x128 tile, 4 waves of 64x64, one-shot K=64.
// Epilogue staged through LDS -> coalesced dwordx4 stores.
#define STSTR_ 136
__global__ __launch_bounds__(256) void p_gemm_mfma(const float* __restrict__ out,
                                                   const _Float16* __restrict__ Bf,
                                                   _Float16* __restrict__ P,
                                                   int n0, int n1) {
    __shared__ _Float16 st[128 * STSTR_];   // 34.8 KB
    int tid = threadIdx.x;
    int lane = tid & 63;
    int wid = tid >> 6;
    int wm = (wid & 1) * 64;
    int wn = (wid >> 1) * 64;
    int mloc0 = blockIdx.y * 128;
    int nbase = blockIdx.x * 128;
    int lrow = lane & 15, quad = lane >> 4;

    halfx8 bfr[4][2];
#pragma unroll
    for (int nf = 0; nf < 4; ++nf)
#pragma unroll
        for (int ks = 0; ks < 2; ++ks) {
            size_t g = (size_t)(nbase + wn + nf * 16 + lrow) * 64 + ks * 32 + quad * 8;
            bfr[nf][ks] = *(const halfx8*)&Bf[g];
        }

    f32x4 acc[4][4];
#pragma unroll
    for (int a = 0; a < 4; ++a)
#pragma unroll
        for (int b = 0; b < 4; ++b) acc[a][b] = (f32x4){0.f, 0.f, 0.f, 0.f};

#pragma unroll
    for (int mf = 0; mf < 4; ++mf) {
        int gm = n0 + mloc0 + wm + mf * 16 + lrow;
        halfx8 af[2];
#pragma unroll
        for (int ks = 0; ks < 2; ++ks) {
            float v[8];
            if (gm < n1) {
                float4 v0 = *(const float4*)&out[(size_t)gm * 64 + ks * 32 + quad * 8];
                float4 v1 = *(const float4*)&out[(size_t)gm * 64 + ks * 32 + quad * 8 + 4];
                v[0] = v0.x; v[1] = v0.y; v[2] = v0.z; v[3] = v0.w;
                v[4] = v1.x; v[5] = v1.y; v[6] = v1.z; v[7] = v1.w;
            } else {
#pragma unroll
                for (int i = 0; i < 8; ++i) v[i] = 0.f;
            }
#pragma unroll
            for (int i = 0; i < 8; ++i) af[ks][i] = (_Float16)v[i];
        }
#pragma unroll
        for (int nf = 0; nf < 4; ++nf) {
#pragma unroll
            for (int ks = 0; ks < 2; ++ks)
                acc[mf][nf] = __builtin_amdgcn_mfma_f32_16x16x32_f16(
                    af[ks], bfr[nf][ks], acc[mf][nf], 0, 0, 0);
        }
    }

    // stage tile in LDS (C/D frag layout col=lane&15, row=quad*4+reg; m89-verified)
#pragma unroll
    for (int mf = 0; mf < 4; ++mf)
#pragma unroll
        for (int nf = 0; nf < 4; ++nf)
#pragma unroll
            for (int r = 0; r < 4; ++r) {
                int row = wm + mf * 16 + quad * 4 + r;
                int col = wn + nf * 16 + lrow;
                st[row * STSTR_ + col] = (_Float16)acc[mf][nf][r];
            }
    __syncthreads();
#pragma unroll
    for (int it = 0; it < 8; ++it) {
        int chunk = it * 256 + tid;
        int row = chunk >> 4;
        int cb = (chunk & 15) * 8;
        if (n0 + mloc0 + row < n1) {
            int4 v = *(const int4*)&st[row * STSTR_ + cb];
            *(int4*)&P[(size_t)(mloc0 + row) * PC_ + nbase + cb] = v;
        }
    }
}

// ---------------------------------------------------------------------------
// edge_msg via fp16 MFMA (unchanged from r10): per src node, msg-block
// (16 edges x 64 o) = H(16x128) @ P_n'(as B[o][k]). Wave per node.
__global__ __launch_bounds__(256) void edge_msg(const _Float16* __restrict__ P,
                                                const _Float16* __restrict__ h1,
                                                const float* __restrict__ Q,
                                                const int* __restrict__ eord,
                                                const int* __restrict__ dst,
                                                const int* __restrict__ src_off,
                                                float* __restrict__ agg,
                                                int n0, int n1) {
    int wv = __builtin_amdgcn_readfirstlane((int)(threadIdx.x >> 6));
    int r = blockIdx.x * 4 + wv;
    int n = n0 + r;
    if (n >= n1) return;
    int lane = threadIdx.x & 63;
    int lrow = lane & 15, quad = lane >> 4;
    int beg = src_off[n], end2 = src_off[n + 1];
    if (beg == end2) return;
    const _Float16* Pr = P + (size_t)r * PC_;

    halfx8 bf[4][4];
#pragma unroll
    for (int nf = 0; nf < 4; ++nf)
#pragma unroll
        for (int ks = 0; ks < 4; ++ks)
            bf[nf][ks] = *(const halfx8*)&Pr[(nf * 16 + lrow) * 128 + ks * 32 + quad * 8];
    float qv[4];
#pragma unroll
    for (int nf = 0; nf < 4; ++nf) qv[nf] = Q[(size_t)n * 64 + nf * 16 + lrow];

    for (int g = beg; g < end2; g += 16) {
        int gcnt = end2 - g; if (gcnt > 16) gcnt = 16;
        int ei = lrow < gcnt ? lrow : gcnt - 1;
        int ej = eord[g + ei];
        int dv = dst[ej];
        halfx8 af[4];
#pragma unroll
        for (int ks = 0; ks < 4; ++ks)
            af[ks] = *(const halfx8*)&h1[(size_t)ej * 128 + ks * 32 + quad * 8];
        f32x4 acc[4];
#pragma unroll
        for (int nf = 0; nf < 4; ++nf) acc[nf] = (f32x4){0.f, 0.f, 0.f, 0.f};
#pragma unroll
        for (int nf = 0; nf < 4; ++nf)
#pragma unroll
            for (int ks = 0; ks < 4; ++ks)
                acc[nf] = __builtin_amdgcn_mfma_f32_16x16x32_f16(
                    af[ks], bf[nf][ks], acc[nf], 0, 0, 0);
#pragma unroll
        for (int rr = 0; rr < 4; ++rr) {
            int j = quad * 4 + rr;
            int d = __shfl(dv, j, 64);
            if (j < gcnt) {
#pragma unroll
                for (int nf = 0; nf < 4; ++nf)
                    atomicAdd(&agg[(size_t)d * 64 + nf * 16 + lrow],
                              acc[nf][rr] + qv[nf]);
            }
        }
    }
}

// combine (scatter-mean + root + bias + relu) and GRU cell
__global__ __launch_bounds__(256) void gru_kernel(float* __restrict__ out,
                                                  const float* __restrict__ agg,
                                                  const float* __restrict__ cnt,
                                                  const float* __restrict__ root,
                                                  const float* __restrict__ cbias,
                                                  const float* __restrict__ wi,
                                                  const float* __restrict__ wh,
                                                  const float* __restrict__ bi,
                                                  const float* __restrict__ bh) {
    __shared__ float root_s[64 * 64];
    __shared__ float h_s[32 * 64];
    __shared__ float m_s[32 * 64];
    int tid = threadIdx.x;
    int lane = tid & 63;
    int wv = __builtin_amdgcn_readfirstlane(tid >> 6);
    int nb = blockIdx.x * 32;
#pragma unroll
    for (int it = 0; it < 4; ++it) {
        int i = it * 1024 + tid * 4;
        *(float4*)&root_s[i] = *(const float4*)&root[i];
    }
#pragma unroll
    for (int it = 0; it < 2; ++it) {
        int i = it * 1024 + tid * 4;
        *(float4*)&h_s[i] = *(const float4*)&out[(size_t)nb * 64 + i];
    }
    __syncthreads();

    int nbase = nb + wv * 8;
    float a[8];
#pragma unroll
    for (int j = 0; j < 8; ++j) {
        int n = nbase + j;
        float c = cnt[n]; c = c > 1.f ? c : 1.f;
        a[j] = agg[(size_t)n * 64 + lane] / c + cbias[lane];
    }
    for (int i = 0; i < 64; ++i) {
        float rv = root_s[i * 64 + lane];
#pragma unroll
        for (int j = 0; j < 8; ++j)
            a[j] = fmaf(h_s[(wv * 8 + j) * 64 + i], rv, a[j]);
    }
#pragma unroll
    for (int j = 0; j < 8; ++j) {
        float m = a[j] > 0.f ? a[j] : 0.f;
        m_s[(wv * 8 + j) * 64 + lane] = m;
    }
    __syncthreads();

    float gir[8], giz[8], gin[8], ghr[8], ghz[8], ghn[8];
    float bi0 = bi[lane], bi1 = bi[64 + lane], bi2 = bi[128 + lane];
    float bh0 = bh[lane], bh1 = bh[64 + lane], bh2 = bh[128 + lane];
#pragma unroll
    for (int j = 0; j < 8; ++j) {
        gir[j] = bi0; giz[j] = bi1; gin[j] = bi2;
        ghr[j] = bh0; ghz[j] = bh1; ghn[j] = bh2;
    }
    for (int i = 0; i < 64; ++i) {
        float w0 = wi[i * 192 + lane];
        float w1 = wi[i * 192 + 64 + lane];
        float w2v = wi[i * 192 + 128 + lane];
        float u0 = wh[i * 192 + lane];
        float u1 = wh[i * 192 + 64 + lane];
        float u2 = wh[i * 192 + 128 + lane];
#pragma unroll
        for (int j = 0; j < 8; ++j) {
            float mi = m_s[(wv * 8 + j) * 64 + i];
            float hi = h_s[(wv * 8 + j) * 64 + i];
            gir[j] = fmaf(mi, w0, gir[j]);
            giz[j] = fmaf(mi, w1, giz[j]);
            gin[j] = fmaf(mi, w2v, gin[j]);
            ghr[j] = fmaf(hi, u0, ghr[j]);
            ghz[j] = fmaf(hi, u1, ghz[j]);
            ghn[j] = fmaf(hi, u2, ghn[j]);
        }
    }
#pragma unroll
    for (int j = 0; j < 8; ++j) {
        int n = nbase + j;
        float rg = 1.f / (1.f + expf(-(gir[j] + ghr[j])));
        float zg = 1.f / (1.f + expf(-(giz[j] + ghz[j])));
        float ng = tanhf(gin[j] + rg * ghn[j]);
        float h = h_s[(wv * 8 + j) * 64 + lane];
        out[(size_t)n * 64 + lane] = (1.f - zg) * ng + zg * h;
    }
}

// Set2Set LSTM cell
__global__ __launch_bounds__(256) void lstm_kernel(const float* __restrict__ q_star,
                                                   float* __restrict__ hl, float* __restrict__ cl,
                                                   const float* __restrict__ wi,
                                                   const float* __restrict__ wh,
                                                   const float* __restrict__ bi,
                                                   const float* __restrict__ bh) {
    int b = blockIdx.x;
    int j = threadIdx.x;
    __shared__ float qs[128], hs[64], g[256];
    if (j < 128) qs[j] = q_star[b * 128 + j];
    if (j < 64) hs[j] = hl[b * 64 + j];
    __syncthreads();
    float acc = bi[j] + bh[j];
#pragma unroll 8
    for (int i = 0; i < 128; ++i) acc = fmaf(qs[i], wi[i * 256 + j], acc);
#pragma unroll 8
    for (int i = 0; i < 64; ++i) acc = fmaf(hs[i], wh[i * 256 + j], acc);
    g[j] = acc;
    __syncthreads();
    if (j < 64) {
        float ig = 1.f / (1.f + expf(-g[j]));
        float fg = 1.f / (1.f + expf(-g[64 + j]));
        float gg = tanhf(g[128 + j]);
        float og = 1.f / (1.f + expf(-g[192 + j]));
        float c = fg * cl[b * 64 + j] + ig * gg;
        cl[b * 64 + j] = c;
        hl[b * 64 + j] = og * tanhf(c);
    }
}

// Set2Set attention
__global__ __launch_bounds__(256) void attn_kernel(const float* __restrict__ out,
                                                   const int* __restrict__ off_b,
                                                   const float* __restrict__ hl,
                                                   float* __restrict__ q_star,
                                                   float* __restrict__ e_ws) {
    int b = blockIdx.x;
    int start = off_b[b], end = off_b[b + 1];
    int t = threadIdx.x;
    __shared__ float q[64];
    __shared__ float red[256];
    __shared__ float racc[256];
    __shared__ float sasum[4];
    if (t < 64) q[t] = hl[b * 64 + t];
    __syncthreads();
    float lmax = -1e30f;
    for (int n = start + t; n < end; n += 256) {
        float acc = 0.f;
#pragma unroll 16
        for (int d2 = 0; d2 < 64; ++d2) acc = fmaf(out[n * 64 + d2], q[d2], acc);
        e_ws[n] = acc;
        lmax = fmaxf(lmax, acc);
    }
    red[t] = lmax;
    __syncthreads();
    for (int s2 = 128; s2 > 0; s2 >>= 1) {
        if (t < s2) red[t] = fmaxf(red[t], red[t + s2]);
        __syncthreads();
    }
    float emax = red[0];
    int w = t >> 6, d = t & 63;
    float rl = 0.f, lasum = 0.f;
    for (int n = start + w; n < end; n += 4) {
        float a = expf(e_ws[n] - emax);
        rl = fmaf(a, out[n * 64 + d], rl);
        if (d == 0) lasum += a;
    }
    racc[t] = rl;
    if (d == 0) sasum[w] = lasum;
    __syncthreads();
    if (t < 64) {
        float r = racc[t] + racc[64 + t] + racc[128 + t] + racc[192 + t];
        float as = sasum[0] + sasum[1] + sasum[2] + sasum[3];
        as = fmaxf(as, 1e-16f);
        q_star[b * 128 + t] = q[t];
        q_star[b * 128 + 64 + t] = r / as;
    }
}

// output head
__global__ __launch_bounds__(64) void head_kernel(const float* __restrict__ q_star,
                                                  const float* __restrict__ w1,
                                                  const float* __restrict__ b1,
                                                  const float* __restrict__ w2,
                                                  const float* __restrict__ b2,
                                                  float* __restrict__ y) {
    int b = blockIdx.x;
    int d = threadIdx.x;
    float qlo = q_star[b * 128 + d];
    float qhi = q_star[b * 128 + 64 + d];
    float acc = b1[d];
#pragma unroll 8
    for (int i = 0; i < 64; ++i) {
        acc = fmaf(__shfl(qlo, i, 64), w1[i * 64 + d], acc);
        acc = fmaf(__shfl(qhi, i, 64), w1[(64 + i) * 64 + d], acc);
    }
    acc = acc > 0.f ? acc : 0.f;
    float p = acc * w2[d];
    for (int off = 32; off > 0; off >>= 1) p += __shfl_down(p, off, 64);
    if (d == 0) y[b] = p + b2[0];
}

extern "C" void kernel_launch(void* const* d_in, const int* in_sizes, int n_in,
                              void* d_out, int out_size, void* d_ws, size_t ws_size,
                              hipStream_t stream) {
    (void)in_sizes; (void)n_in; (void)out_size;
    const float* x        = (const float*)d_in[0];
    const float* ea       = (const float*)d_in[1];
    const int*   eidx     = (const int*)d_in[2];
    const int*   batch    = (const int*)d_in[3];
    const float* lin0_w   = (const float*)d_in[4];
    const float* lin0_b   = (const float*)d_in[5];
    const float* mlp_w1   = (const float*)d_in[6];
    const float* mlp_b1   = (const float*)d_in[7];
    const float* mlp_w2   = (const float*)d_in[8];
    const float* mlp_b2   = (const float*)d_in[9];
    const float* conv_root= (const float*)d_in[10];
    const float* conv_bias= (const float*)d_in[11];
    const float* gru_wi   = (const float*)d_in[12];
    const float* gru_wh   = (const float*)d_in[13];
    const float* gru_bi   = (const float*)d_in[14];
    const float* gru_bh   = (const float*)d_in[15];
    const float* lstm_wi  = (const float*)d_in[16];
    const float* lstm_wh  = (const float*)d_in[17];
    const float* lstm_bi  = (const float*)d_in[18];
    const float* lstm_bh  = (const float*)d_in[19];
    const float* lin1_w   = (const float*)d_in[20];
    const float* lin1_b   = (const float*)d_in[21];
    const float* lin2_w   = (const float*)d_in[22];
    const float* lin2_b   = (const float*)d_in[23];
    float* y = (float*)d_out;

    const int* src = eidx;
    const int* dst = eidx + E_;

    char* w = (char*)d_ws;
    auto carve = [&](size_t bytes) {
        char* p = w;
        w += (bytes + 255) & ~(size_t)255;
        return p;
    };
    float* out_buf = (float*)carve((size_t)N_ * DIM_ * 4);
    float* agg     = (float*)carve((size_t)N_ * DIM_ * 4);
    float* Q       = (float*)carve((size_t)N_ * DIM_ * 4);
    float* e_ws    = (float*)carve((size_t)N_ * 4);
    int*   off_b   = (int*)carve((size_t)(B_ + 1) * 4);
    _Float16* h1   = (_Float16*)carve((size_t)E_ * MLP_H_ * 2);
    _Float16* Bf   = (_Float16*)carve((size_t)PC_ * 64 * 2);
    int*   src_off = (int*)carve((size_t)(N_ + 1) * 4);
    int*   eord    = (int*)carve((size_t)E_ * 4);
    // contiguous zero zone (single memset)
    char*  zero0   = w;
    float* cnt     = (float*)carve((size_t)N_ * 4);
    int*   cnt_src = (int*)carve((size_t)N_ * 4);
    int*   cur     = (int*)carve((size_t)N_ * 4);
    float* q_star  = (float*)carve((size_t)B_ * 128 * 4);
    float* hl      = (float*)carve((size_t)B_ * 64 * 4);
    float* cl      = (float*)carve((size_t)B_ * 64 * 4);
    size_t zbytes  = (size_t)(w - zero0);

    size_t used = (size_t)(w - (char*)d_ws);
    _Float16* P = (_Float16*)w;
    size_t avail = ws_size > used ? ws_size - used : 0;
    long long nc = (long long)(avail / ((size_t)PC_ * 2));   // fp16 P rows
    if (nc > N_) nc = N_;
    nc &= ~127LL;
    if (nc < 128) nc = 128;
    // balance chunks: equal sizes, multiple of 128
    int nchunks = (N_ + (int)nc - 1) / (int)nc;
    int NC = ((N_ + nchunks - 1) / nchunks + 127) & ~127;

    hipMemsetAsync(zero0, 0, zbytes, stream);

    lin0_kernel<<<(N_ * DIM_ + 255) / 256, 256, 0, stream>>>(x, lin0_w, lin0_b, out_buf);
    mlp1_kernel<<<(E_ * MLP_H_ + 255) / 256, 256, 0, stream>>>(ea, mlp_w1, mlp_b1, h1);
    cnt_kernel<<<(E_ + 255) / 256, 256, 0, stream>>>(dst, cnt);
    batch_off_kernel<<<1, 256, 0, stream>>>(batch, off_b);
    hist_src<<<(E_ + 255) / 256, 256, 0, stream>>>(src, cnt_src);
    scan_src<<<1, 256, 0, stream>>>(cnt_src, src_off);
    scatter_src<<<(E_ + 255) / 256, 256, 0, stream>>>(src, cur, src_off, eord);
    prep_b<<<(PC_ * 64 + 255) / 256, 256, 0, stream>>>(mlp_w2, Bf);

    for (int step = 0; step < 3; ++step) {
        q_kernel<<<(N_ + 3) / 4, 256, 0, stream>>>(out_buf, mlp_b2, Q);
        hipMemsetAsync(agg, 0, (size_t)N_ * DIM_ * 4, stream);
        for (int n0 = 0; n0 < N_; n0 += NC) {
            int n1 = n0 + NC < N_ ? n0 + NC : N_;
            dim3 g(PC_ / 128, (n1 - n0 + 127) / 128);
            p_gemm_mfma<<<g, 256, 0, stream>>>(out_buf, Bf, P, n0, n1);
            int nn = n1 - n0;
            edge_msg<<<(nn + 3) / 4, 256, 0, stream>>>(P, h1, Q, eord, dst,
                                                       src_off, agg, n0, n1);
        }
        gru_kernel<<<N_ / 32, 256, 0, stream>>>(out_buf, agg, cnt, conv_root, conv_bias,
                                                gru_wi, gru_wh, gru_bi, gru_bh);
    }

    for (int s = 0; s < 3; ++s) {
        lstm_kernel<<<B_, 256, 0, stream>>>(q_star, hl, cl, lstm_wi, lstm_wh, lstm_bi, lstm_bh);
        attn_kernel<<<B_, 256, 0, stream>>>(out_buf, off_b, hl, q_star, e_ws);
    }
    head_kernel<<<B_, 64, 0, stream>>>(q_star, lin1_w, lin1_b, lin2_w, lin2_b, y);
}